// Round 4
// baseline (552.912 us; speedup 1.0000x reference)
//
#include <hip/hip_runtime.h>
#include <hip/hip_cooperative_groups.h>
#include <math.h>

namespace cg = cooperative_groups;

// Problem constants
#define NB   512   // B
#define NH   64    // H = E = HP
#define OBS  8
#define PRE  12

// small f32 param pack offsets (elements)
#define OFF_WREL  0     // 128
#define OFF_BREL  128   // 64
#define OFF_BPOOL 192   // 64
#define OFF_WPOS  256   // 128
#define OFF_BPOS  384   // 2
#define OFF_WEMB  386   // 128
#define OFF_BEMB  514   // 64
#define OFF_BIH   578   // 192
#define OFF_BHH   770   // 192
#define OFF_FLAG  962   // 1: 1.0 if buffers are f32, 0.0 if bf16
#define N_SMALL   963

typedef __bf16 bf16x8 __attribute__((ext_vector_type(8)));
typedef float  f32x4  __attribute__((ext_vector_type(4)));

union FragU { bf16x8 v; unsigned short u[8]; };

__device__ __forceinline__ float bf2f(unsigned short u) {
  unsigned int x = ((unsigned int)u) << 16;
  return __builtin_bit_cast(float, x);
}
__device__ __forceinline__ unsigned short f2bf(float f) {
  unsigned int u = __builtin_bit_cast(unsigned int, f);
  u += 0x7FFFu + ((u >> 16) & 1u);   // RNE
  return (unsigned short)(u >> 16);
}
// dtype-branched accessors (flag uniform per wave -> no divergence cost)
__device__ __forceinline__ float ldf(const void* p, int i, bool isf32) {
  return isf32 ? ((const float*)p)[i] : bf2f(((const unsigned short*)p)[i]);
}
__device__ __forceinline__ unsigned short ld16(const void* p, int i, bool isf32) {
  return isf32 ? f2bf(((const float*)p)[i]) : ((const unsigned short*)p)[i];
}
__device__ __forceinline__ void stout(void* p, int i, float v, bool isf32) {
  if (isf32) ((float*)p)[i] = v;
  else       ((unsigned short*)p)[i] = f2bf(v);
}

// ===========================================================================
// FUSED cooperative kernel: prep + 12 decoder iterations with grid.sync()
// grid: 256 blocks x 512 threads (8 waves; block handles i0=2*bid, i1=2*bid+1)
// ===========================================================================
struct FusedArgs {
  const void *hidden_state, *group_track, *W_emb, *b_emb, *W_ih, *W_hh,
             *b_ih, *b_hh, *W_pos, *b_pos, *W_rel, *b_rel, *W_pool, *b_pool;
  float *last0, *last1;
  unsigned short *hbf0, *hbf1;
  float *h_carry, *WTf;
  unsigned short *Wp_bf;
  float *smallf;
  void *out;
};

__global__ __launch_bounds__(512, 2) void fused_kernel(FusedArgs a)
{
  cg::grid_group grid = cg::this_grid();
  const int tid  = threadIdx.x;
  const int lane = tid & 63;
  const int wave = tid >> 6;
  const int col  = lane & 15;   // MFMA m/n index
  const int quad = lane >> 4;   // k-group selector
  const int gid  = blockIdx.x * 512 + tid;

  __shared__ float red[8][64];

  // ---- dtype detect (per wave, uniform; see R2 analysis) ----
  int bad = 0;
  const unsigned short* hs16 = (const unsigned short*)a.hidden_state;
  for (int k = lane; k < 256; k += 64) {
    unsigned e = (hs16[k] >> 7) & 0xFFu;
    bad |= (e >= 0x8Eu) ? 1 : 0;
  }
  const bool isf32 = (__ballot(bad) != 0ULL);

  // ---- prep: canonicalize inputs into ws (one pass, every launch) ----
  if (gid < 32768) {                       // per-agent state: i = gid>>6, o = gid&63
    int i = gid >> 6, o = gid & 63;
    a.h_carry[gid] = 0.0f;
    a.hbf0[gid] = ld16(a.hidden_state, gid, isf32);
    if (o < 16) stout(a.out, i * 40 + o, ldf(a.group_track, i * 16 + o, isf32), isf32);
    if (o < 2)  a.last0[i * 2 + o] = ldf(a.group_track, i * 16 + 14 + o, isf32);
  } else if (gid < 57344) {                // transposed GRU weights (24576)
    int u = gid - 32768;
    int k = u / 384, c = u % 384;
    a.WTf[u] = (c < 192) ? ldf(a.W_ih, c * 64 + k, isf32)
                         : ldf(a.W_hh, (c - 192) * 64 + k, isf32);
  } else if (gid < 65536) {                // bf16 W_pool (8192)
    int u = gid - 57344;
    a.Wp_bf[u] = ld16(a.W_pool, u, isf32);
  } else if (gid < 65536 + N_SMALL) {      // small param pack
    int u = gid - 65536;
    float v;
    if      (u < 128) v = ldf(a.W_rel,  u,        isf32);
    else if (u < 192) v = ldf(a.b_rel,  u - 128,  isf32);
    else if (u < 256) v = ldf(a.b_pool, u - 192,  isf32);
    else if (u < 384) v = ldf(a.W_pos,  u - 256,  isf32);
    else if (u < 386) v = ldf(a.b_pos,  u - 384,  isf32);
    else if (u < 514) v = ldf(a.W_emb,  u - 386,  isf32);
    else if (u < 578) v = ldf(a.b_emb,  u - 514,  isf32);
    else if (u < 770) v = ldf(a.b_ih,   u - 578,  isf32);
    else if (u < 962) v = ldf(a.b_hh,   u - 770,  isf32);
    else              v = isf32 ? 1.0f : 0.0f;
    a.smallf[u] = v;
  }

  grid.sync();   // canonical buffers ready, device-wide

  // ---- load loop-invariant weights into registers ONCE ----
  float wr0[2][8], wr1[2][8], brl[2][8];
  #pragma unroll
  for (int ks = 0; ks < 2; ++ks) {
    int kb = ks * 32 + quad * 8;
    #pragma unroll
    for (int j = 0; j < 8; ++j) {
      wr0[ks][j] = a.smallf[OFF_WREL + kb + j];
      wr1[ks][j] = a.smallf[OFF_WREL + 64 + kb + j];
      brl[ks][j] = a.smallf[OFF_BREL + kb + j];
    }
  }
  float bp[4];
  #pragma unroll
  for (int nt = 0; nt < 4; ++nt) bp[nt] = a.smallf[OFF_BPOOL + nt * 16 + col];

  FragU bw[4][4];   // B-fragments of W_pool (K=128): B[ks*32+quad*8+j][nt*16+col]
  #pragma unroll
  for (int nt = 0; nt < 4; ++nt)
    #pragma unroll
    for (int ks = 0; ks < 4; ++ks)
      #pragma unroll
      for (int j = 0; j < 8; ++j)
        bw[nt][ks].u[j] = a.Wp_bf[(ks * 32 + quad * 8 + j) * 64 + nt * 16 + col];

  const int iw  = 2 * blockIdx.x + (wave >> 2);  // this wave's agent i
  const int jb0 = (wave & 3) * 128;              // this wave's j-range start

  // ---- 12 decoder iterations ----
  for (int t = 0; t < PRE; ++t) {
    const int p = t & 1;
    const float* last_in  = p ? a.last1 : a.last0;
    float*       last_out = p ? a.last0 : a.last1;
    const unsigned short* hbf_in  = p ? a.hbf1 : a.hbf0;
    unsigned short*       hbf_out = p ? a.hbf0 : a.hbf1;

    const float2* lp = (const float2*)last_in;
    const float2  li = lp[iw];

    // prefetch this wave's 128 last-positions (covers all 4 sub-tiles)
    float2 l0s[4], l1s[4];
    #pragma unroll
    for (int s = 0; s < 4; ++s) {
      l0s[s] = lp[jb0 + s * 32 + col];
      l1s[s] = lp[jb0 + s * 32 + 16 + col];
    }

    float vmax[4] = {0.f, 0.f, 0.f, 0.f};  // relu output >= 0, so 0 is safe

    for (int s = 0; s < 4; ++s) {
      const int jb = jb0 + s * 32;
      const float d0x = l0s[s].x - li.x, d0y = l0s[s].y - li.y;
      const float d1x = l1s[s].x - li.x, d1y = l1s[s].y - li.y;

      // e-part A-fragments (K rows 0..63), built in registers, native bf16 cvt
      bf16x8 aE[2][2];
      #pragma unroll
      for (int ks = 0; ks < 2; ++ks) {
        #pragma unroll
        for (int j = 0; j < 8; ++j) {
          float e0 = fmaxf(fmaf(d0y, wr1[ks][j], fmaf(d0x, wr0[ks][j], brl[ks][j])), 0.f);
          float e1 = fmaxf(fmaf(d1y, wr1[ks][j], fmaf(d1x, wr0[ks][j], brl[ks][j])), 0.f);
          aE[0][ks][j] = (__bf16)e0;
          aE[1][ks][j] = (__bf16)e1;
        }
      }
      // h-part A-fragments (K rows 64..127): vector loads from bf16 h matrix
      bf16x8 aH[2][2];
      #pragma unroll
      for (int mt = 0; mt < 2; ++mt) {
        int jr = jb + mt * 16 + col;
        #pragma unroll
        for (int ks = 0; ks < 2; ++ks)
          aH[mt][ks] = *(const bf16x8*)(hbf_in + jr * 64 + ks * 32 + quad * 8);
      }

      f32x4 acc[2][4];
      #pragma unroll
      for (int mt = 0; mt < 2; ++mt)
        #pragma unroll
        for (int nt = 0; nt < 4; ++nt)
          acc[mt][nt] = (f32x4){0.f, 0.f, 0.f, 0.f};

      #pragma unroll
      for (int nt = 0; nt < 4; ++nt)
        #pragma unroll
        for (int mt = 0; mt < 2; ++mt) {
          acc[mt][nt] = __builtin_amdgcn_mfma_f32_16x16x32_bf16(aE[mt][0], bw[nt][0].v, acc[mt][nt], 0, 0, 0);
          acc[mt][nt] = __builtin_amdgcn_mfma_f32_16x16x32_bf16(aE[mt][1], bw[nt][1].v, acc[mt][nt], 0, 0, 0);
          acc[mt][nt] = __builtin_amdgcn_mfma_f32_16x16x32_bf16(aH[mt][0], bw[nt][2].v, acc[mt][nt], 0, 0, 0);
          acc[mt][nt] = __builtin_amdgcn_mfma_f32_16x16x32_bf16(aH[mt][1], bw[nt][3].v, acc[mt][nt], 0, 0, 0);
        }

      #pragma unroll
      for (int mt = 0; mt < 2; ++mt)
        #pragma unroll
        for (int nt = 0; nt < 4; ++nt)
          #pragma unroll
          for (int r = 0; r < 4; ++r) {
            float v = acc[mt][nt][r] + bp[nt];
            vmax[nt] = fmaxf(fmaxf(v, 0.f), vmax[nt]);
          }
    }

    // reduce over rows within wave, then across the 4 waves of this i via LDS
    #pragma unroll
    for (int nt = 0; nt < 4; ++nt) {
      vmax[nt] = fmaxf(vmax[nt], __shfl_xor(vmax[nt], 16, 64));
      vmax[nt] = fmaxf(vmax[nt], __shfl_xor(vmax[nt], 32, 64));
    }
    if (lane < 16) {
      #pragma unroll
      for (int nt = 0; nt < 4; ++nt) red[wave][nt * 16 + lane] = vmax[nt];
    }
    __syncthreads();

    // ---- head: waves 0 (i0) and 4 (i1) ----
    if ((wave & 3) == 0) {
      const int o = lane;
      const int i = iw;
      float pooled = fmaxf(fmaxf(red[wave][o], red[wave + 1][o]),
                           fmaxf(red[wave + 2][o], red[wave + 3][o]));
      float p0 = pooled * a.smallf[OFF_WPOS + o * 2 + 0];
      float p1 = pooled * a.smallf[OFF_WPOS + o * 2 + 1];
      #pragma unroll
      for (int sft = 32; sft >= 1; sft >>= 1) {
        p0 += __shfl_xor(p0, sft, 64);
        p1 += __shfl_xor(p1, sft, 64);
      }
      p0 += a.smallf[OFF_BPOS + 0];
      p1 += a.smallf[OFF_BPOS + 1];
      if (o == 0) {
        stout(a.out, i * 40 + (OBS + t) * 2 + 0, p0, isf32);
        stout(a.out, i * 40 + (OBS + t) * 2 + 1, p1, isf32);
        last_out[2 * i]     = p0;
        last_out[2 * i + 1] = p1;
      }
      // GRU: lane o computes gate element o of each of the 6 mat-vecs
      float gir = 0.f, giz = 0.f, gin = 0.f, ghr = 0.f, ghz = 0.f, ghn = 0.f;
      #pragma unroll 8
      for (int k = 0; k < 64; ++k) {
        float ek = p0 * a.smallf[OFF_WEMB + k] + p1 * a.smallf[OFF_WEMB + 64 + k]
                 + a.smallf[OFF_BEMB + k];          // uniform
        float hk = a.h_carry[i * 64 + k];           // uniform
        const float* w = a.WTf + k * 384;           // coalesced across lanes
        gir += ek * w[o];
        giz += ek * w[64 + o];
        gin += ek * w[128 + o];
        ghr += hk * w[192 + o];
        ghz += hk * w[256 + o];
        ghn += hk * w[320 + o];
      }
      gir += a.smallf[OFF_BIH + o];       ghr += a.smallf[OFF_BHH + o];
      giz += a.smallf[OFF_BIH + 64 + o];  ghz += a.smallf[OFF_BHH + 64 + o];
      gin += a.smallf[OFF_BIH + 128 + o]; ghn += a.smallf[OFF_BHH + 128 + o];
      float r = 1.f / (1.f + __expf(-(gir + ghr)));
      float z = 1.f / (1.f + __expf(-(giz + ghz)));
      float n = tanhf(gin + r * ghn);
      float hp = a.h_carry[i * 64 + o];
      float hn = (1.f - z) * n + z * hp;
      a.h_carry[i * 64 + o] = hn;
      hbf_out[i * 64 + o] = f2bf(hn);
    }

    if (t < PRE - 1) grid.sync();   // uniform condition; last iter needs no sync
  }
}

// ===========================================================================
// R3 FALLBACK PATH (proven passing): prep + 12 pair kernels
// ===========================================================================
__global__ __launch_bounds__(64) void prep_kernel(
    const void* __restrict__ hidden_state, const void* __restrict__ group_track,
    const void* __restrict__ W_emb,  const void* __restrict__ b_emb,
    const void* __restrict__ W_ih,   const void* __restrict__ W_hh,
    const void* __restrict__ b_ih,   const void* __restrict__ b_hh,
    const void* __restrict__ W_pos,  const void* __restrict__ b_pos,
    const void* __restrict__ W_rel,  const void* __restrict__ b_rel,
    const void* __restrict__ W_pool, const void* __restrict__ b_pool,
    float* __restrict__ last0, unsigned short* __restrict__ hbf0,
    float* __restrict__ h_carry, float* __restrict__ WTf,
    unsigned short* __restrict__ Wp_bf, float* __restrict__ smallf,
    void* __restrict__ out)
{
  const int b = blockIdx.x;
  const int o = threadIdx.x;
  int bad = 0;
  const unsigned short* hs16 = (const unsigned short*)hidden_state;
  for (int k = o; k < 256; k += 64) {
    unsigned e = (hs16[k] >> 7) & 0xFFu;
    bad |= (e >= 0x8Eu) ? 1 : 0;
  }
  const bool isf32 = (__ballot(bad) != 0ULL);

  hbf0[b * 64 + o] = ld16(hidden_state, b * 64 + o, isf32);
  h_carry[b * 64 + o] = 0.0f;
  if (o < 16) stout(out, b * 40 + o, ldf(group_track, b * 16 + o, isf32), isf32);
  if (o < 2)  last0[b * 2 + o] = ldf(group_track, b * 16 + 14 + o, isf32);

  if (b < 384) {
    int u = b * 64 + o;
    int k = u / 384, c = u % 384;
    WTf[u] = (c < 192) ? ldf(W_ih, c * 64 + k, isf32)
                       : ldf(W_hh, (c - 192) * 64 + k, isf32);
  } else {
    int u = (b - 384) * 64 + o;
    Wp_bf[u] = ld16(W_pool, u, isf32);
  }
  if (b < 16) {
    int u = b * 64 + o;
    if (u < N_SMALL) {
      float v;
      if      (u < 128) v = ldf(W_rel,  u,        isf32);
      else if (u < 192) v = ldf(b_rel,  u - 128,  isf32);
      else if (u < 256) v = ldf(b_pool, u - 192,  isf32);
      else if (u < 384) v = ldf(W_pos,  u - 256,  isf32);
      else if (u < 386) v = ldf(b_pos,  u - 384,  isf32);
      else if (u < 514) v = ldf(W_emb,  u - 386,  isf32);
      else if (u < 578) v = ldf(b_emb,  u - 514,  isf32);
      else if (u < 770) v = ldf(b_ih,   u - 578,  isf32);
      else if (u < 962) v = ldf(b_hh,   u - 770,  isf32);
      else              v = isf32 ? 1.0f : 0.0f;
      smallf[u] = v;
    }
  }
}

__global__ __launch_bounds__(256) void pair_kernel(
    const float* __restrict__ smallf,
    const unsigned short* __restrict__ Wp_bf,
    const float* __restrict__ WTf,
    const float* __restrict__ last_in, float* __restrict__ last_out,
    const unsigned short* __restrict__ hbf_in, unsigned short* __restrict__ hbf_out,
    float* __restrict__ h_carry, void* __restrict__ out, int t)
{
  const int i    = blockIdx.x;
  const int tid  = threadIdx.x;
  const int lane = tid & 63;
  const int wave = tid >> 6;
  const int col  = lane & 15;
  const int quad = lane >> 4;

  __shared__ float red[4][64];

  const float2* lp = (const float2*)last_in;
  const float2  li = lp[i];

  float wr0[2][8], wr1[2][8], brl[2][8];
  #pragma unroll
  for (int ks = 0; ks < 2; ++ks) {
    int kb = ks * 32 + quad * 8;
    #pragma unroll
    for (int j = 0; j < 8; ++j) {
      wr0[ks][j] = smallf[OFF_WREL + kb + j];
      wr1[ks][j] = smallf[OFF_WREL + 64 + kb + j];
      brl[ks][j] = smallf[OFF_BREL + kb + j];
    }
  }
  float bp[4];
  #pragma unroll
  for (int nt = 0; nt < 4; ++nt) bp[nt] = smallf[OFF_BPOOL + nt * 16 + col];

  FragU bw[4][4];
  #pragma unroll
  for (int nt = 0; nt < 4; ++nt)
    #pragma unroll
    for (int ks = 0; ks < 4; ++ks)
      #pragma unroll
      for (int j = 0; j < 8; ++j)
        bw[nt][ks].u[j] = Wp_bf[(ks * 32 + quad * 8 + j) * 64 + nt * 16 + col];

  float vmax[4] = {0.f, 0.f, 0.f, 0.f};
  const int jb0 = wave * 128;
  for (int s = 0; s < 4; ++s) {
    const int jb = jb0 + s * 32;
    const float2 l0 = lp[jb + col], l1 = lp[jb + 16 + col];
    const float d0x = l0.x - li.x, d0y = l0.y - li.y;
    const float d1x = l1.x - li.x, d1y = l1.y - li.y;

    bf16x8 aE[2][2];
    #pragma unroll
    for (int ks = 0; ks < 2; ++ks)
      #pragma unroll
      for (int j = 0; j < 8; ++j) {
        float e0 = fmaxf(fmaf(d0y, wr1[ks][j], fmaf(d0x, wr0[ks][j], brl[ks][j])), 0.f);
        float e1 = fmaxf(fmaf(d1y, wr1[ks][j], fmaf(d1x, wr0[ks][j], brl[ks][j])), 0.f);
        aE[0][ks][j] = (__bf16)e0;
        aE[1][ks][j] = (__bf16)e1;
      }
    bf16x8 aH[2][2];
    #pragma unroll
    for (int mt = 0; mt < 2; ++mt) {
      int jr = jb + mt * 16 + col;
      #pragma unroll
      for (int ks = 0; ks < 2; ++ks)
        aH[mt][ks] = *(const bf16x8*)(hbf_in + jr * 64 + ks * 32 + quad * 8);
    }

    f32x4 acc[2][4];
    #pragma unroll
    for (int mt = 0; mt < 2; ++mt)
      #pragma unroll
      for (int nt = 0; nt < 4; ++nt)
        acc[mt][nt] = (f32x4){0.f, 0.f, 0.f, 0.f};

    #pragma unroll
    for (int nt = 0; nt < 4; ++nt)
      #pragma unroll
      for (int mt = 0; mt < 2; ++mt) {
        acc[mt][nt] = __builtin_amdgcn_mfma_f32_16x16x32_bf16(aE[mt][0], bw[nt][0].v, acc[mt][nt], 0, 0, 0);
        acc[mt][nt] = __builtin_amdgcn_mfma_f32_16x16x32_bf16(aE[mt][1], bw[nt][1].v, acc[mt][nt], 0, 0, 0);
        acc[mt][nt] = __builtin_amdgcn_mfma_f32_16x16x32_bf16(aH[mt][0], bw[nt][2].v, acc[mt][nt], 0, 0, 0);
        acc[mt][nt] = __builtin_amdgcn_mfma_f32_16x16x32_bf16(aH[mt][1], bw[nt][3].v, acc[mt][nt], 0, 0, 0);
      }

    #pragma unroll
    for (int mt = 0; mt < 2; ++mt)
      #pragma unroll
      for (int nt = 0; nt < 4; ++nt)
        #pragma unroll
        for (int r = 0; r < 4; ++r) {
          float v = acc[mt][nt][r] + bp[nt];
          vmax[nt] = fmaxf(fmaxf(v, 0.f), vmax[nt]);
        }
  }

  #pragma unroll
  for (int nt = 0; nt < 4; ++nt) {
    vmax[nt] = fmaxf(vmax[nt], __shfl_xor(vmax[nt], 16, 64));
    vmax[nt] = fmaxf(vmax[nt], __shfl_xor(vmax[nt], 32, 64));
  }
  if (lane < 16) {
    #pragma unroll
    for (int nt = 0; nt < 4; ++nt) red[wave][nt * 16 + lane] = vmax[nt];
  }
  __syncthreads();

  if (tid < 64) {
    const int o = tid;
    const bool isf32 = (smallf[OFF_FLAG] != 0.0f);
    float pooled = fmaxf(fmaxf(red[0][o], red[1][o]), fmaxf(red[2][o], red[3][o]));
    float p0 = pooled * smallf[OFF_WPOS + o * 2 + 0];
    float p1 = pooled * smallf[OFF_WPOS + o * 2 + 1];
    #pragma unroll
    for (int sft = 32; sft >= 1; sft >>= 1) {
      p0 += __shfl_xor(p0, sft, 64);
      p1 += __shfl_xor(p1, sft, 64);
    }
    p0 += smallf[OFF_BPOS + 0];
    p1 += smallf[OFF_BPOS + 1];
    if (o == 0) {
      stout(out, i * 40 + (OBS + t) * 2 + 0, p0, isf32);
      stout(out, i * 40 + (OBS + t) * 2 + 1, p1, isf32);
      last_out[2 * i]     = p0;
      last_out[2 * i + 1] = p1;
    }
    float gir = 0.f, giz = 0.f, gin = 0.f, ghr = 0.f, ghz = 0.f, ghn = 0.f;
    #pragma unroll 8
    for (int k = 0; k < 64; ++k) {
      float ek = p0 * smallf[OFF_WEMB + k] + p1 * smallf[OFF_WEMB + 64 + k]
               + smallf[OFF_BEMB + k];
      float hk = h_carry[i * 64 + k];
      const float* w = WTf + k * 384;
      gir += ek * w[o];
      giz += ek * w[64 + o];
      gin += ek * w[128 + o];
      ghr += hk * w[192 + o];
      ghz += hk * w[256 + o];
      ghn += hk * w[320 + o];
    }
    gir += smallf[OFF_BIH + o];       ghr += smallf[OFF_BHH + o];
    giz += smallf[OFF_BIH + 64 + o];  ghz += smallf[OFF_BHH + 64 + o];
    gin += smallf[OFF_BIH + 128 + o]; ghn += smallf[OFF_BHH + 128 + o];
    float r = 1.f / (1.f + __expf(-(gir + ghr)));
    float z = 1.f / (1.f + __expf(-(giz + ghz)));
    float n = tanhf(gin + r * ghn);
    float hp = h_carry[i * 64 + o];
    float hn = (1.f - z) * n + z * hp;
    h_carry[i * 64 + o] = hn;
    hbf_out[i * 64 + o] = f2bf(hn);
  }
}

// ---------------------------------------------------------------------------
extern "C" void kernel_launch(void* const* d_in, const int* in_sizes, int n_in,
                              void* d_out, int out_size, void* d_ws, size_t ws_size,
                              hipStream_t stream) {
  (void)in_sizes; (void)n_in; (void)out_size; (void)ws_size;
  const void* hidden_state = d_in[0];
  const void* group_track  = d_in[1];
  const void* W_emb  = d_in[2];
  const void* b_emb  = d_in[3];
  const void* W_ih   = d_in[4];
  const void* W_hh   = d_in[5];
  const void* b_ih   = d_in[6];
  const void* b_hh   = d_in[7];
  const void* W_pos  = d_in[8];
  const void* b_pos  = d_in[9];
  const void* W_rel  = d_in[10];
  const void* b_rel  = d_in[11];
  const void* W_pool = d_in[12];
  const void* b_pool = d_in[13];

  char* ws = (char*)d_ws;
  float* last[2]          = {(float*)(ws + 0),      (float*)(ws + 4096)};
  unsigned short* hbf[2]  = {(unsigned short*)(ws + 8192),
                             (unsigned short*)(ws + 73728)};
  float* h_carry          = (float*)(ws + 139264);
  float* WTf              = (float*)(ws + 270336);          // 98304 B
  unsigned short* Wp_bf   = (unsigned short*)(ws + 368640); // 16384 B
  float* smallf           = (float*)(ws + 385024);          // ~3856 B

  FusedArgs fa;
  fa.hidden_state = hidden_state; fa.group_track = group_track;
  fa.W_emb = W_emb; fa.b_emb = b_emb; fa.W_ih = W_ih; fa.W_hh = W_hh;
  fa.b_ih = b_ih; fa.b_hh = b_hh; fa.W_pos = W_pos; fa.b_pos = b_pos;
  fa.W_rel = W_rel; fa.b_rel = b_rel; fa.W_pool = W_pool; fa.b_pool = b_pool;
  fa.last0 = last[0]; fa.last1 = last[1];
  fa.hbf0 = hbf[0]; fa.hbf1 = hbf[1];
  fa.h_carry = h_carry; fa.WTf = WTf; fa.Wp_bf = Wp_bf; fa.smallf = smallf;
  fa.out = d_out;

  void* params[] = { &fa };
  hipError_t err = hipLaunchCooperativeKernel((const void*)fused_kernel,
                                              dim3(256), dim3(512),
                                              params, 0, stream);
  if (err != hipSuccess) {
    // Fallback: proven 13-kernel path (identical math)
    prep_kernel<<<512, 64, 0, stream>>>(hidden_state, group_track,
                                        W_emb, b_emb, W_ih, W_hh, b_ih, b_hh,
                                        W_pos, b_pos, W_rel, b_rel, W_pool, b_pool,
                                        last[0], hbf[0], h_carry, WTf, Wp_bf,
                                        smallf, d_out);
    for (int t = 0; t < PRE; ++t) {
      int p = t & 1;
      pair_kernel<<<512, 256, 0, stream>>>(smallf, Wp_bf, WTf,
                                           last[p], last[1 - p],
                                           hbf[p], hbf[1 - p],
                                           h_carry, d_out, t);
    }
  }
}

// Round 5
// 368.495 us; speedup vs baseline: 1.5005x; 1.5005x over previous
//
#include <hip/hip_runtime.h>
#include <hip/hip_cooperative_groups.h>
#include <math.h>

namespace cg = cooperative_groups;

// Problem constants
#define NB   512   // B
#define NH   64    // H = E = HP
#define OBS  8
#define PRE  12

// small f32 param pack offsets (elements)
#define OFF_WREL  0     // 128
#define OFF_BREL  128   // 64
#define OFF_BPOOL 192   // 64
#define OFF_WPOS  256   // 128
#define OFF_BPOS  384   // 2
#define OFF_WEMB  386   // 128
#define OFF_BEMB  514   // 64
#define OFF_BIH   578   // 192
#define OFF_BHH   770   // 192
#define OFF_FLAG  962   // 1: 1.0 if buffers are f32, 0.0 if bf16
#define N_SMALL   963

typedef __bf16 bf16x8 __attribute__((ext_vector_type(8)));
typedef float  f32x4  __attribute__((ext_vector_type(4)));

union FragU { bf16x8 v; unsigned short u[8]; };

__device__ __forceinline__ float bf2f(unsigned short u) {
  unsigned int x = ((unsigned int)u) << 16;
  return __builtin_bit_cast(float, x);
}
__device__ __forceinline__ unsigned short f2bf(float f) {
  unsigned int u = __builtin_bit_cast(unsigned int, f);
  u += 0x7FFFu + ((u >> 16) & 1u);   // RNE
  return (unsigned short)(u >> 16);
}
__device__ __forceinline__ float ldf(const void* p, int i, bool isf32) {
  return isf32 ? ((const float*)p)[i] : bf2f(((const unsigned short*)p)[i]);
}
__device__ __forceinline__ unsigned short ld16(const void* p, int i, bool isf32) {
  return isf32 ? f2bf(((const float*)p)[i]) : ((const unsigned short*)p)[i];
}
__device__ __forceinline__ void stout(void* p, int i, float v, bool isf32) {
  if (isf32) ((float*)p)[i] = v;
  else       ((unsigned short*)p)[i] = f2bf(v);
}

// ---------------------------------------------------------------------------
// Lightweight grid barrier: per-barrier counter (pre-zeroed by hipMemsetAsync).
// RELEASE fetch_add pushes this XCD's dirty L2 (~9 KB) to the coherence point;
// RELAXED spin polls L3 without invalidating anything; one ACQUIRE fence on
// exit invalidates L1/L2 so subsequent normal loads see fresh state.
// Requires all blocks co-resident (cooperative launch, grid = 256 = #CUs).
// ---------------------------------------------------------------------------
__device__ __forceinline__ void gbar(unsigned int* cnt, unsigned int nblk) {
  __syncthreads();                       // all waves' stores issued (vmcnt drained per-wave)
  if (threadIdx.x == 0) {
    __hip_atomic_fetch_add(cnt, 1u, __ATOMIC_RELEASE, __HIP_MEMORY_SCOPE_AGENT);
    while (__hip_atomic_load(cnt, __ATOMIC_RELAXED, __HIP_MEMORY_SCOPE_AGENT) < nblk) {
      __builtin_amdgcn_s_sleep(2);
    }
    __builtin_amdgcn_fence(__ATOMIC_ACQUIRE, "agent");
  }
  __syncthreads();
}

// ===========================================================================
// FUSED cooperative kernel: prep + 12 decoder iterations, custom barrier
// grid: 256 blocks x 512 threads (8 waves; block handles i0=2*bid, i1=2*bid+1)
// ===========================================================================
struct FusedArgs {
  const void *hidden_state, *group_track, *W_emb, *b_emb, *W_ih, *W_hh,
             *b_ih, *b_hh, *W_pos, *b_pos, *W_rel, *b_rel, *W_pool, *b_pool;
  float *last0, *last1;
  unsigned short *hbf0, *hbf1;
  float *WTf;
  unsigned short *Wp_bf;
  float *smallf;
  unsigned int *cnts;    // 13 pre-zeroed barrier counters
  void *out;
};

__global__ __launch_bounds__(512, 2) void fused_kernel(FusedArgs a)
{
  const int tid  = threadIdx.x;
  const int lane = tid & 63;
  const int wave = tid >> 6;
  const int col  = lane & 15;   // MFMA m/n index
  const int quad = lane >> 4;   // k-group selector
  const int gid  = blockIdx.x * 512 + tid;

  __shared__ float red[8][64];

  // ---- dtype detect (per wave, uniform; see R2 analysis) ----
  int bad = 0;
  const unsigned short* hs16 = (const unsigned short*)a.hidden_state;
  for (int k = lane; k < 256; k += 64) {
    unsigned e = (hs16[k] >> 7) & 0xFFu;
    bad |= (e >= 0x8Eu) ? 1 : 0;
  }
  const bool isf32 = (__ballot(bad) != 0ULL);

  // ---- prep: canonicalize inputs into ws (one pass, every launch) ----
  if (gid < 32768) {                       // per-agent state: i = gid>>6, o = gid&63
    int i = gid >> 6, o = gid & 63;
    a.hbf0[gid] = ld16(a.hidden_state, gid, isf32);
    if (o < 16) stout(a.out, i * 40 + o, ldf(a.group_track, i * 16 + o, isf32), isf32);
    if (o < 2)  a.last0[i * 2 + o] = ldf(a.group_track, i * 16 + 14 + o, isf32);
  } else if (gid < 57344) {                // transposed GRU weights (24576)
    int u = gid - 32768;
    int k = u / 384, c = u % 384;
    a.WTf[u] = (c < 192) ? ldf(a.W_ih, c * 64 + k, isf32)
                         : ldf(a.W_hh, (c - 192) * 64 + k, isf32);
  } else if (gid < 65536) {                // bf16 W_pool (8192)
    int u = gid - 57344;
    a.Wp_bf[u] = ld16(a.W_pool, u, isf32);
  } else if (gid < 65536 + N_SMALL) {      // small param pack
    int u = gid - 65536;
    float v;
    if      (u < 128) v = ldf(a.W_rel,  u,        isf32);
    else if (u < 192) v = ldf(a.b_rel,  u - 128,  isf32);
    else if (u < 256) v = ldf(a.b_pool, u - 192,  isf32);
    else if (u < 384) v = ldf(a.W_pos,  u - 256,  isf32);
    else if (u < 386) v = ldf(a.b_pos,  u - 384,  isf32);
    else if (u < 514) v = ldf(a.W_emb,  u - 386,  isf32);
    else if (u < 578) v = ldf(a.b_emb,  u - 514,  isf32);
    else if (u < 770) v = ldf(a.b_ih,   u - 578,  isf32);
    else if (u < 962) v = ldf(a.b_hh,   u - 770,  isf32);
    else              v = isf32 ? 1.0f : 0.0f;
    a.smallf[u] = v;
  }

  gbar(&a.cnts[0], 256);   // canonical buffers visible device-wide

  // ---- load loop-invariant weights into registers ONCE ----
  float wr0[2][8], wr1[2][8], brl[2][8];
  #pragma unroll
  for (int ks = 0; ks < 2; ++ks) {
    int kb = ks * 32 + quad * 8;
    #pragma unroll
    for (int j = 0; j < 8; ++j) {
      wr0[ks][j] = a.smallf[OFF_WREL + kb + j];
      wr1[ks][j] = a.smallf[OFF_WREL + 64 + kb + j];
      brl[ks][j] = a.smallf[OFF_BREL + kb + j];
    }
  }
  float bp[4];
  #pragma unroll
  for (int nt = 0; nt < 4; ++nt) bp[nt] = a.smallf[OFF_BPOOL + nt * 16 + col];

  FragU bw[4][4];   // B-fragments of W_pool (K=128): B[ks*32+quad*8+j][nt*16+col]
  #pragma unroll
  for (int nt = 0; nt < 4; ++nt)
    #pragma unroll
    for (int ks = 0; ks < 4; ++ks)
      #pragma unroll
      for (int j = 0; j < 8; ++j)
        bw[nt][ks].u[j] = a.Wp_bf[(ks * 32 + quad * 8 + j) * 64 + nt * 16 + col];

  const int iw  = 2 * blockIdx.x + (wave >> 2);  // this wave's agent i
  const int jb0 = (wave & 3) * 128;              // this wave's j-range start

  float hreg = 0.0f;   // GRU carry for agent iw, lane `lane` (head waves only)

  // ---- 12 decoder iterations ----
  for (int t = 0; t < PRE; ++t) {
    const int p = t & 1;
    const float* last_in  = p ? a.last1 : a.last0;
    float*       last_out = p ? a.last0 : a.last1;
    const unsigned short* hbf_in  = p ? a.hbf1 : a.hbf0;
    unsigned short*       hbf_out = p ? a.hbf0 : a.hbf1;

    const float2* lp = (const float2*)last_in;
    const float2  li = lp[iw];

    // prefetch this wave's 128 last-positions (covers all 4 sub-tiles)
    float2 l0s[4], l1s[4];
    #pragma unroll
    for (int s = 0; s < 4; ++s) {
      l0s[s] = lp[jb0 + s * 32 + col];
      l1s[s] = lp[jb0 + s * 32 + 16 + col];
    }

    float vmax[4] = {0.f, 0.f, 0.f, 0.f};  // relu output >= 0, so 0 is safe

    for (int s = 0; s < 4; ++s) {
      const int jb = jb0 + s * 32;
      const float d0x = l0s[s].x - li.x, d0y = l0s[s].y - li.y;
      const float d1x = l1s[s].x - li.x, d1y = l1s[s].y - li.y;

      // e-part A-fragments (K rows 0..63), built in registers
      bf16x8 aE[2][2];
      #pragma unroll
      for (int ks = 0; ks < 2; ++ks) {
        #pragma unroll
        for (int j = 0; j < 8; ++j) {
          float e0 = fmaxf(fmaf(d0y, wr1[ks][j], fmaf(d0x, wr0[ks][j], brl[ks][j])), 0.f);
          float e1 = fmaxf(fmaf(d1y, wr1[ks][j], fmaf(d1x, wr0[ks][j], brl[ks][j])), 0.f);
          aE[0][ks][j] = (__bf16)e0;
          aE[1][ks][j] = (__bf16)e1;
        }
      }
      // h-part A-fragments (K rows 64..127): vector loads from bf16 h matrix
      bf16x8 aH[2][2];
      #pragma unroll
      for (int mt = 0; mt < 2; ++mt) {
        int jr = jb + mt * 16 + col;
        #pragma unroll
        for (int ks = 0; ks < 2; ++ks)
          aH[mt][ks] = *(const bf16x8*)(hbf_in + jr * 64 + ks * 32 + quad * 8);
      }

      f32x4 acc[2][4];
      #pragma unroll
      for (int mt = 0; mt < 2; ++mt)
        #pragma unroll
        for (int nt = 0; nt < 4; ++nt)
          acc[mt][nt] = (f32x4){0.f, 0.f, 0.f, 0.f};

      #pragma unroll
      for (int nt = 0; nt < 4; ++nt)
        #pragma unroll
        for (int mt = 0; mt < 2; ++mt) {
          acc[mt][nt] = __builtin_amdgcn_mfma_f32_16x16x32_bf16(aE[mt][0], bw[nt][0].v, acc[mt][nt], 0, 0, 0);
          acc[mt][nt] = __builtin_amdgcn_mfma_f32_16x16x32_bf16(aE[mt][1], bw[nt][1].v, acc[mt][nt], 0, 0, 0);
          acc[mt][nt] = __builtin_amdgcn_mfma_f32_16x16x32_bf16(aH[mt][0], bw[nt][2].v, acc[mt][nt], 0, 0, 0);
          acc[mt][nt] = __builtin_amdgcn_mfma_f32_16x16x32_bf16(aH[mt][1], bw[nt][3].v, acc[mt][nt], 0, 0, 0);
        }

      #pragma unroll
      for (int mt = 0; mt < 2; ++mt)
        #pragma unroll
        for (int nt = 0; nt < 4; ++nt)
          #pragma unroll
          for (int r = 0; r < 4; ++r) {
            float v = acc[mt][nt][r] + bp[nt];
            vmax[nt] = fmaxf(fmaxf(v, 0.f), vmax[nt]);
          }
    }

    // reduce over rows within wave, then across the 4 waves of this i via LDS
    #pragma unroll
    for (int nt = 0; nt < 4; ++nt) {
      vmax[nt] = fmaxf(vmax[nt], __shfl_xor(vmax[nt], 16, 64));
      vmax[nt] = fmaxf(vmax[nt], __shfl_xor(vmax[nt], 32, 64));
    }
    if (lane < 16) {
      #pragma unroll
      for (int nt = 0; nt < 4; ++nt) red[wave][nt * 16 + lane] = vmax[nt];
    }
    __syncthreads();

    // ---- head: waves 0 (i0) and 4 (i1) ----
    if ((wave & 3) == 0) {
      const int o = lane;
      const int i = iw;
      float pooled = fmaxf(fmaxf(red[wave][o], red[wave + 1][o]),
                           fmaxf(red[wave + 2][o], red[wave + 3][o]));
      float p0 = pooled * a.smallf[OFF_WPOS + o * 2 + 0];
      float p1 = pooled * a.smallf[OFF_WPOS + o * 2 + 1];
      #pragma unroll
      for (int sft = 32; sft >= 1; sft >>= 1) {
        p0 += __shfl_xor(p0, sft, 64);
        p1 += __shfl_xor(p1, sft, 64);
      }
      p0 += a.smallf[OFF_BPOS + 0];
      p1 += a.smallf[OFF_BPOS + 1];
      if (o == 0) {
        stout(a.out, i * 40 + (OBS + t) * 2 + 0, p0, isf32);
        stout(a.out, i * 40 + (OBS + t) * 2 + 1, p1, isf32);
        last_out[2 * i]     = p0;
        last_out[2 * i + 1] = p1;
      }
      // GRU: lane o computes gate element o; h carried in registers (__shfl bcast)
      float gir = 0.f, giz = 0.f, gin = 0.f, ghr = 0.f, ghz = 0.f, ghn = 0.f;
      #pragma unroll 8
      for (int k = 0; k < 64; ++k) {
        float ek = p0 * a.smallf[OFF_WEMB + k] + p1 * a.smallf[OFF_WEMB + 64 + k]
                 + a.smallf[OFF_BEMB + k];          // uniform
        float hk = __shfl(hreg, k, 64);             // uniform broadcast
        const float* w = a.WTf + k * 384;           // coalesced across lanes
        gir += ek * w[o];
        giz += ek * w[64 + o];
        gin += ek * w[128 + o];
        ghr += hk * w[192 + o];
        ghz += hk * w[256 + o];
        ghn += hk * w[320 + o];
      }
      gir += a.smallf[OFF_BIH + o];       ghr += a.smallf[OFF_BHH + o];
      giz += a.smallf[OFF_BIH + 64 + o];  ghz += a.smallf[OFF_BHH + 64 + o];
      gin += a.smallf[OFF_BIH + 128 + o]; ghn += a.smallf[OFF_BHH + 128 + o];
      float r = 1.f / (1.f + __expf(-(gir + ghr)));
      float z = 1.f / (1.f + __expf(-(giz + ghz)));
      float n = tanhf(gin + r * ghn);
      float hn = (1.f - z) * n + z * hreg;
      hreg = hn;
      hbf_out[i * 64 + o] = f2bf(hn);
    }

    if (t < PRE - 1) gbar(&a.cnts[1 + t], 256);
  }
}

// ===========================================================================
// R3 FALLBACK PATH (proven passing): prep + 12 pair kernels
// ===========================================================================
__global__ __launch_bounds__(64) void prep_kernel(
    const void* __restrict__ hidden_state, const void* __restrict__ group_track,
    const void* __restrict__ W_emb,  const void* __restrict__ b_emb,
    const void* __restrict__ W_ih,   const void* __restrict__ W_hh,
    const void* __restrict__ b_ih,   const void* __restrict__ b_hh,
    const void* __restrict__ W_pos,  const void* __restrict__ b_pos,
    const void* __restrict__ W_rel,  const void* __restrict__ b_rel,
    const void* __restrict__ W_pool, const void* __restrict__ b_pool,
    float* __restrict__ last0, unsigned short* __restrict__ hbf0,
    float* __restrict__ h_carry, float* __restrict__ WTf,
    unsigned short* __restrict__ Wp_bf, float* __restrict__ smallf,
    void* __restrict__ out)
{
  const int b = blockIdx.x;
  const int o = threadIdx.x;
  int bad = 0;
  const unsigned short* hs16 = (const unsigned short*)hidden_state;
  for (int k = o; k < 256; k += 64) {
    unsigned e = (hs16[k] >> 7) & 0xFFu;
    bad |= (e >= 0x8Eu) ? 1 : 0;
  }
  const bool isf32 = (__ballot(bad) != 0ULL);

  hbf0[b * 64 + o] = ld16(hidden_state, b * 64 + o, isf32);
  h_carry[b * 64 + o] = 0.0f;
  if (o < 16) stout(out, b * 40 + o, ldf(group_track, b * 16 + o, isf32), isf32);
  if (o < 2)  last0[b * 2 + o] = ldf(group_track, b * 16 + 14 + o, isf32);

  if (b < 384) {
    int u = b * 64 + o;
    int k = u / 384, c = u % 384;
    WTf[u] = (c < 192) ? ldf(W_ih, c * 64 + k, isf32)
                       : ldf(W_hh, (c - 192) * 64 + k, isf32);
  } else {
    int u = (b - 384) * 64 + o;
    Wp_bf[u] = ld16(W_pool, u, isf32);
  }
  if (b < 16) {
    int u = b * 64 + o;
    if (u < N_SMALL) {
      float v;
      if      (u < 128) v = ldf(W_rel,  u,        isf32);
      else if (u < 192) v = ldf(b_rel,  u - 128,  isf32);
      else if (u < 256) v = ldf(b_pool, u - 192,  isf32);
      else if (u < 384) v = ldf(W_pos,  u - 256,  isf32);
      else if (u < 386) v = ldf(b_pos,  u - 384,  isf32);
      else if (u < 514) v = ldf(W_emb,  u - 386,  isf32);
      else if (u < 578) v = ldf(b_emb,  u - 514,  isf32);
      else if (u < 770) v = ldf(b_ih,   u - 578,  isf32);
      else if (u < 962) v = ldf(b_hh,   u - 770,  isf32);
      else              v = isf32 ? 1.0f : 0.0f;
      smallf[u] = v;
    }
  }
}

__global__ __launch_bounds__(256) void pair_kernel(
    const float* __restrict__ smallf,
    const unsigned short* __restrict__ Wp_bf,
    const float* __restrict__ WTf,
    const float* __restrict__ last_in, float* __restrict__ last_out,
    const unsigned short* __restrict__ hbf_in, unsigned short* __restrict__ hbf_out,
    float* __restrict__ h_carry, void* __restrict__ out, int t)
{
  const int i    = blockIdx.x;
  const int tid  = threadIdx.x;
  const int lane = tid & 63;
  const int wave = tid >> 6;
  const int col  = lane & 15;
  const int quad = lane >> 4;

  __shared__ float red[4][64];

  const float2* lp = (const float2*)last_in;
  const float2  li = lp[i];

  float wr0[2][8], wr1[2][8], brl[2][8];
  #pragma unroll
  for (int ks = 0; ks < 2; ++ks) {
    int kb = ks * 32 + quad * 8;
    #pragma unroll
    for (int j = 0; j < 8; ++j) {
      wr0[ks][j] = smallf[OFF_WREL + kb + j];
      wr1[ks][j] = smallf[OFF_WREL + 64 + kb + j];
      brl[ks][j] = smallf[OFF_BREL + kb + j];
    }
  }
  float bp[4];
  #pragma unroll
  for (int nt = 0; nt < 4; ++nt) bp[nt] = smallf[OFF_BPOOL + nt * 16 + col];

  FragU bw[4][4];
  #pragma unroll
  for (int nt = 0; nt < 4; ++nt)
    #pragma unroll
    for (int ks = 0; ks < 4; ++ks)
      #pragma unroll
      for (int j = 0; j < 8; ++j)
        bw[nt][ks].u[j] = Wp_bf[(ks * 32 + quad * 8 + j) * 64 + nt * 16 + col];

  float vmax[4] = {0.f, 0.f, 0.f, 0.f};
  const int jb0 = wave * 128;
  for (int s = 0; s < 4; ++s) {
    const int jb = jb0 + s * 32;
    const float2 l0 = lp[jb + col], l1 = lp[jb + 16 + col];
    const float d0x = l0.x - li.x, d0y = l0.y - li.y;
    const float d1x = l1.x - li.x, d1y = l1.y - li.y;

    bf16x8 aE[2][2];
    #pragma unroll
    for (int ks = 0; ks < 2; ++ks)
      #pragma unroll
      for (int j = 0; j < 8; ++j) {
        float e0 = fmaxf(fmaf(d0y, wr1[ks][j], fmaf(d0x, wr0[ks][j], brl[ks][j])), 0.f);
        float e1 = fmaxf(fmaf(d1y, wr1[ks][j], fmaf(d1x, wr0[ks][j], brl[ks][j])), 0.f);
        aE[0][ks][j] = (__bf16)e0;
        aE[1][ks][j] = (__bf16)e1;
      }
    bf16x8 aH[2][2];
    #pragma unroll
    for (int mt = 0; mt < 2; ++mt) {
      int jr = jb + mt * 16 + col;
      #pragma unroll
      for (int ks = 0; ks < 2; ++ks)
        aH[mt][ks] = *(const bf16x8*)(hbf_in + jr * 64 + ks * 32 + quad * 8);
    }

    f32x4 acc[2][4];
    #pragma unroll
    for (int mt = 0; mt < 2; ++mt)
      #pragma unroll
      for (int nt = 0; nt < 4; ++nt)
        acc[mt][nt] = (f32x4){0.f, 0.f, 0.f, 0.f};

    #pragma unroll
    for (int nt = 0; nt < 4; ++nt)
      #pragma unroll
      for (int mt = 0; mt < 2; ++mt) {
        acc[mt][nt] = __builtin_amdgcn_mfma_f32_16x16x32_bf16(aE[mt][0], bw[nt][0].v, acc[mt][nt], 0, 0, 0);
        acc[mt][nt] = __builtin_amdgcn_mfma_f32_16x16x32_bf16(aE[mt][1], bw[nt][1].v, acc[mt][nt], 0, 0, 0);
        acc[mt][nt] = __builtin_amdgcn_mfma_f32_16x16x32_bf16(aH[mt][0], bw[nt][2].v, acc[mt][nt], 0, 0, 0);
        acc[mt][nt] = __builtin_amdgcn_mfma_f32_16x16x32_bf16(aH[mt][1], bw[nt][3].v, acc[mt][nt], 0, 0, 0);
      }

    #pragma unroll
    for (int mt = 0; mt < 2; ++mt)
      #pragma unroll
      for (int nt = 0; nt < 4; ++nt)
        #pragma unroll
        for (int r = 0; r < 4; ++r) {
          float v = acc[mt][nt][r] + bp[nt];
          vmax[nt] = fmaxf(fmaxf(v, 0.f), vmax[nt]);
        }
  }

  #pragma unroll
  for (int nt = 0; nt < 4; ++nt) {
    vmax[nt] = fmaxf(vmax[nt], __shfl_xor(vmax[nt], 16, 64));
    vmax[nt] = fmaxf(vmax[nt], __shfl_xor(vmax[nt], 32, 64));
  }
  if (lane < 16) {
    #pragma unroll
    for (int nt = 0; nt < 4; ++nt) red[wave][nt * 16 + lane] = vmax[nt];
  }
  __syncthreads();

  if (tid < 64) {
    const int o = tid;
    const bool isf32 = (smallf[OFF_FLAG] != 0.0f);
    float pooled = fmaxf(fmaxf(red[0][o], red[1][o]), fmaxf(red[2][o], red[3][o]));
    float p0 = pooled * smallf[OFF_WPOS + o * 2 + 0];
    float p1 = pooled * smallf[OFF_WPOS + o * 2 + 1];
    #pragma unroll
    for (int sft = 32; sft >= 1; sft >>= 1) {
      p0 += __shfl_xor(p0, sft, 64);
      p1 += __shfl_xor(p1, sft, 64);
    }
    p0 += smallf[OFF_BPOS + 0];
    p1 += smallf[OFF_BPOS + 1];
    if (o == 0) {
      stout(out, i * 40 + (OBS + t) * 2 + 0, p0, isf32);
      stout(out, i * 40 + (OBS + t) * 2 + 1, p1, isf32);
      last_out[2 * i]     = p0;
      last_out[2 * i + 1] = p1;
    }
    float gir = 0.f, giz = 0.f, gin = 0.f, ghr = 0.f, ghz = 0.f, ghn = 0.f;
    #pragma unroll 8
    for (int k = 0; k < 64; ++k) {
      float ek = p0 * smallf[OFF_WEMB + k] + p1 * smallf[OFF_WEMB + 64 + k]
               + smallf[OFF_BEMB + k];
      float hk = h_carry[i * 64 + k];
      const float* w = WTf + k * 384;
      gir += ek * w[o];
      giz += ek * w[64 + o];
      gin += ek * w[128 + o];
      ghr += hk * w[192 + o];
      ghz += hk * w[256 + o];
      ghn += hk * w[320 + o];
    }
    gir += smallf[OFF_BIH + o];       ghr += smallf[OFF_BHH + o];
    giz += smallf[OFF_BIH + 64 + o];  ghz += smallf[OFF_BHH + 64 + o];
    gin += smallf[OFF_BIH + 128 + o]; ghn += smallf[OFF_BHH + 128 + o];
    float r = 1.f / (1.f + __expf(-(gir + ghr)));
    float z = 1.f / (1.f + __expf(-(giz + ghz)));
    float n = tanhf(gin + r * ghn);
    float hp = h_carry[i * 64 + o];
    float hn = (1.f - z) * n + z * hp;
    h_carry[i * 64 + o] = hn;
    hbf_out[i * 64 + o] = f2bf(hn);
  }
}

// ---------------------------------------------------------------------------
extern "C" void kernel_launch(void* const* d_in, const int* in_sizes, int n_in,
                              void* d_out, int out_size, void* d_ws, size_t ws_size,
                              hipStream_t stream) {
  (void)in_sizes; (void)n_in; (void)out_size; (void)ws_size;
  const void* hidden_state = d_in[0];
  const void* group_track  = d_in[1];
  const void* W_emb  = d_in[2];
  const void* b_emb  = d_in[3];
  const void* W_ih   = d_in[4];
  const void* W_hh   = d_in[5];
  const void* b_ih   = d_in[6];
  const void* b_hh   = d_in[7];
  const void* W_pos  = d_in[8];
  const void* b_pos  = d_in[9];
  const void* W_rel  = d_in[10];
  const void* b_rel  = d_in[11];
  const void* W_pool = d_in[12];
  const void* b_pool = d_in[13];

  char* ws = (char*)d_ws;
  float* last[2]          = {(float*)(ws + 0),      (float*)(ws + 4096)};
  unsigned short* hbf[2]  = {(unsigned short*)(ws + 8192),
                             (unsigned short*)(ws + 73728)};
  float* h_carry          = (float*)(ws + 139264);          // fallback path only
  float* WTf              = (float*)(ws + 270336);          // 98304 B
  unsigned short* Wp_bf   = (unsigned short*)(ws + 368640); // 16384 B
  float* smallf           = (float*)(ws + 385024);          // ~3856 B
  unsigned int* cnts      = (unsigned int*)(ws + 401408);   // 13 barrier counters

  // zero the barrier counters (graph-capturable async memset)
  hipMemsetAsync(cnts, 0, 64, stream);

  FusedArgs fa;
  fa.hidden_state = hidden_state; fa.group_track = group_track;
  fa.W_emb = W_emb; fa.b_emb = b_emb; fa.W_ih = W_ih; fa.W_hh = W_hh;
  fa.b_ih = b_ih; fa.b_hh = b_hh; fa.W_pos = W_pos; fa.b_pos = b_pos;
  fa.W_rel = W_rel; fa.b_rel = b_rel; fa.W_pool = W_pool; fa.b_pool = b_pool;
  fa.last0 = last[0]; fa.last1 = last[1];
  fa.hbf0 = hbf[0]; fa.hbf1 = hbf[1];
  fa.WTf = WTf; fa.Wp_bf = Wp_bf; fa.smallf = smallf;
  fa.cnts = cnts; fa.out = d_out;

  void* params[] = { &fa };
  hipError_t err = hipLaunchCooperativeKernel((const void*)fused_kernel,
                                              dim3(256), dim3(512),
                                              params, 0, stream);
  if (err != hipSuccess) {
    // Fallback: proven 13-kernel path (identical math)
    prep_kernel<<<512, 64, 0, stream>>>(hidden_state, group_track,
                                        W_emb, b_emb, W_ih, W_hh, b_ih, b_hh,
                                        W_pos, b_pos, W_rel, b_rel, W_pool, b_pool,
                                        last[0], hbf[0], h_carry, WTf, Wp_bf,
                                        smallf, d_out);
    for (int t = 0; t < PRE; ++t) {
      int p = t & 1;
      pair_kernel<<<512, 256, 0, stream>>>(smallf, Wp_bf, WTf,
                                           last[p], last[1 - p],
                                           hbf[p], hbf[1 - p],
                                           h_carry, d_out, t);
    }
  }
}

// Round 6
// 336.355 us; speedup vs baseline: 1.6438x; 1.0956x over previous
//
#include <hip/hip_runtime.h>
#include <math.h>

// Problem constants
#define NB   512   // B
#define NH   64    // H = E = HP
#define OBS  8
#define PRE  12

// small f32 param pack offsets (elements)
#define OFF_WREL  0     // 128
#define OFF_BREL  128   // 64
#define OFF_BPOOL 192   // 64
#define OFF_WPOS  256   // 128
#define OFF_BPOS  384   // 2
#define OFF_WEMB  386   // 128
#define OFF_BEMB  514   // 64
#define OFF_BIH   578   // 192
#define OFF_BHH   770   // 192
#define OFF_FLAG  962   // 1: 1.0 if buffers are f32, 0.0 if bf16
#define N_SMALL   963

typedef __bf16 bf16x8 __attribute__((ext_vector_type(8)));
typedef float  f32x4  __attribute__((ext_vector_type(4)));

union FragU { bf16x8 v; unsigned short u[8]; };

__device__ __forceinline__ float bf2f(unsigned short u) {
  unsigned int x = ((unsigned int)u) << 16;
  return __builtin_bit_cast(float, x);
}
__device__ __forceinline__ unsigned short f2bf(float f) {
  unsigned int u = __builtin_bit_cast(unsigned int, f);
  u += 0x7FFFu + ((u >> 16) & 1u);   // RNE
  return (unsigned short)(u >> 16);
}
__device__ __forceinline__ float ldf(const void* p, int i, bool isf32) {
  return isf32 ? ((const float*)p)[i] : bf2f(((const unsigned short*)p)[i]);
}
__device__ __forceinline__ unsigned short ld16(const void* p, int i, bool isf32) {
  return isf32 ? f2bf(((const float*)p)[i]) : ((const unsigned short*)p)[i];
}
__device__ __forceinline__ void stout(void* p, int i, float v, bool isf32) {
  if (isf32) ((float*)p)[i] = v;
  else       ((unsigned short*)p)[i] = f2bf(v);
}

// ---- coherent (write-through / cache-bypass) helpers: relaxed agent atomics
__device__ __forceinline__ void ast32(unsigned int* p, unsigned int v) {
  __hip_atomic_store(p, v, __ATOMIC_RELAXED, __HIP_MEMORY_SCOPE_AGENT);
}
__device__ __forceinline__ void ast64(unsigned long long* p, unsigned long long v) {
  __hip_atomic_store(p, v, __ATOMIC_RELAXED, __HIP_MEMORY_SCOPE_AGENT);
}
__device__ __forceinline__ float2 ald_f2(const float2* p) {
  union { unsigned long long q; float2 f; } u;
  u.q = __hip_atomic_load((const unsigned long long*)p, __ATOMIC_RELAXED,
                          __HIP_MEMORY_SCOPE_AGENT);
  return u.f;
}
__device__ __forceinline__ bf16x8 ald_bf8(const unsigned short* p) {
  union { unsigned long long q[2]; bf16x8 v; } u;
  const unsigned long long* qp = (const unsigned long long*)p;
  u.q[0] = __hip_atomic_load(qp + 0, __ATOMIC_RELAXED, __HIP_MEMORY_SCOPE_AGENT);
  u.q[1] = __hip_atomic_load(qp + 1, __ATOMIC_RELAXED, __HIP_MEMORY_SCOPE_AGENT);
  return u.v;
}

// ---------------------------------------------------------------------------
// Fence-free grid barrier. All cross-block data uses write-through atomic
// stores (never dirty in L2) and cache-bypassing atomic loads, so no
// buffer_wbl2 / buffer_inv (L2 tag scans, ~13 us each — the R5 cost) needed.
// s_waitcnt(0) guarantees each wave's stores are ack'd at the coherence point
// before its barrier entry; thread 0 then arrives and spins relaxed.
// Requires all 256 blocks co-resident (cooperative launch).
// ---------------------------------------------------------------------------
__device__ __forceinline__ void gbar(unsigned int* cnt, unsigned int nblk) {
  __builtin_amdgcn_s_waitcnt(0);         // drain this wave's vm/lgkm counters
  __syncthreads();
  if (threadIdx.x == 0) {
    __hip_atomic_fetch_add(cnt, 1u, __ATOMIC_RELAXED, __HIP_MEMORY_SCOPE_AGENT);
    while (__hip_atomic_load(cnt, __ATOMIC_RELAXED, __HIP_MEMORY_SCOPE_AGENT) < nblk)
      __builtin_amdgcn_s_sleep(1);
  }
  __syncthreads();
}

// ===========================================================================
// FUSED cooperative kernel: prep + 12 decoder iterations, fence-free barriers
// grid: 256 blocks x 512 threads. Block handles agents i0=2*bid, i1=2*bid+1.
// Wave w covers j-rows [w*64,(w+1)*64) for BOTH agents (shares aH loads).
// ===========================================================================
struct FusedArgs {
  const void *hidden_state, *group_track, *W_emb, *b_emb, *W_ih, *W_hh,
             *b_ih, *b_hh, *W_pos, *b_pos, *W_rel, *b_rel, *W_pool, *b_pool;
  float *last0, *last1;
  unsigned short *hbf0, *hbf1;
  float *WTf;
  unsigned short *Wp_bf;
  float *smallf;
  unsigned int *cnts;    // 13 pre-zeroed barrier counters
  void *out;
};

__global__ __launch_bounds__(512, 2) void fused_kernel(FusedArgs a)
{
  const int tid  = threadIdx.x;
  const int lane = tid & 63;
  const int wave = tid >> 6;
  const int col  = lane & 15;   // MFMA m/n index
  const int quad = lane >> 4;   // k-group selector
  const int gid  = blockIdx.x * 512 + tid;
  const int i0   = 2 * blockIdx.x;

  __shared__ float red[8][2][64];

  // ---- dtype detect (per wave, uniform) ----
  int bad = 0;
  const unsigned short* hs16 = (const unsigned short*)a.hidden_state;
  for (int k = lane; k < 256; k += 64) {
    unsigned e = (hs16[k] >> 7) & 0xFFu;
    bad |= (e >= 0x8Eu) ? 1 : 0;
  }
  const bool isf32 = (__ballot(bad) != 0ULL);

  // ---- prep: canonicalize inputs into ws, all via write-through stores ----
  if (gid < 16384) {                        // hbf0: 16384 uint pairs (32768 bf16)
    unsigned int pk = ((unsigned int)ld16(a.hidden_state, 2 * gid + 1, isf32) << 16)
                    | ld16(a.hidden_state, 2 * gid, isf32);
    ast32((unsigned int*)a.hbf0 + gid, pk);
  } else if (gid < 16896) {                 // last0: 512 agents, 8B each
    int g = gid - 16384;
    union { unsigned long long q; float2 f; } u;
    u.f.x = ldf(a.group_track, g * 16 + 14, isf32);
    u.f.y = ldf(a.group_track, g * 16 + 15, isf32);
    ast64((unsigned long long*)(a.last0 + 2 * g), u.q);
  } else if (gid < 25088) {                 // out[:, :8, :] copy (plain stores)
    int g = gid - 16896;
    int i = g >> 4, o = g & 15;
    stout(a.out, i * 40 + o, ldf(a.group_track, i * 16 + o, isf32), isf32);
  } else if (gid >= 32768 && gid < 57344) { // transposed GRU weights (24576 f32)
    int u = gid - 32768;
    int k = u / 384, c = u % 384;
    float v = (c < 192) ? ldf(a.W_ih, c * 64 + k, isf32)
                        : ldf(a.W_hh, (c - 192) * 64 + k, isf32);
    ast32((unsigned int*)(a.WTf + u), __builtin_bit_cast(unsigned int, v));
  } else if (gid >= 57344 && gid < 61440) { // bf16 W_pool: 4096 uint pairs
    int u = gid - 57344;
    unsigned int pk = ((unsigned int)ld16(a.W_pool, 2 * u + 1, isf32) << 16)
                    | ld16(a.W_pool, 2 * u, isf32);
    ast32((unsigned int*)a.Wp_bf + u, pk);
  } else if (gid >= 61440 && gid < 61440 + N_SMALL) {  // small param pack
    int u = gid - 61440;
    float v;
    if      (u < 128) v = ldf(a.W_rel,  u,        isf32);
    else if (u < 192) v = ldf(a.b_rel,  u - 128,  isf32);
    else if (u < 256) v = ldf(a.b_pool, u - 192,  isf32);
    else if (u < 384) v = ldf(a.W_pos,  u - 256,  isf32);
    else if (u < 386) v = ldf(a.b_pos,  u - 384,  isf32);
    else if (u < 514) v = ldf(a.W_emb,  u - 386,  isf32);
    else if (u < 578) v = ldf(a.b_emb,  u - 514,  isf32);
    else if (u < 770) v = ldf(a.b_ih,   u - 578,  isf32);
    else if (u < 962) v = ldf(a.b_hh,   u - 770,  isf32);
    else              v = isf32 ? 1.0f : 0.0f;
    ast32((unsigned int*)(a.smallf + u), __builtin_bit_cast(unsigned int, v));
  }

  gbar(&a.cnts[0], 256);   // ws canonical; weights now plain-cacheable (cold L2)

  // ---- load loop-invariant weights into registers ONCE (plain cached) ----
  float wr0[2][8], wr1[2][8], brl[2][8];
  #pragma unroll
  for (int ks = 0; ks < 2; ++ks) {
    int kb = ks * 32 + quad * 8;
    #pragma unroll
    for (int j = 0; j < 8; ++j) {
      wr0[ks][j] = a.smallf[OFF_WREL + kb + j];
      wr1[ks][j] = a.smallf[OFF_WREL + 64 + kb + j];
      brl[ks][j] = a.smallf[OFF_BREL + kb + j];
    }
  }
  float bp[4];
  #pragma unroll
  for (int nt = 0; nt < 4; ++nt) bp[nt] = a.smallf[OFF_BPOOL + nt * 16 + col];

  FragU bw[4][4];   // B-fragments of W_pool (K=128): B[ks*32+quad*8+j][nt*16+col]
  #pragma unroll
  for (int nt = 0; nt < 4; ++nt)
    #pragma unroll
    for (int ks = 0; ks < 4; ++ks)
      #pragma unroll
      for (int j = 0; j < 8; ++j)
        bw[nt][ks].u[j] = a.Wp_bf[(ks * 32 + quad * 8 + j) * 64 + nt * 16 + col];

  float hreg = 0.0f;   // GRU carry for this head wave's agent (waves 0 and 4)

  // ---- 12 decoder iterations ----
  for (int t = 0; t < PRE; ++t) {
    const int p = t & 1;
    const float* last_in  = p ? a.last1 : a.last0;
    float*       last_out = p ? a.last0 : a.last1;
    const unsigned short* hbf_in  = p ? a.hbf1 : a.hbf0;
    unsigned short*       hbf_out = p ? a.hbf0 : a.hbf1;

    const float2* lp = (const float2*)last_in;
    const float2 liA = ald_f2(lp + i0);
    const float2 liB = ald_f2(lp + i0 + 1);

    float vmax[2][4] = {{0.f,0.f,0.f,0.f},{0.f,0.f,0.f,0.f}};

    for (int s = 0; s < 2; ++s) {
      const int jb = wave * 64 + s * 32;
      const float2 l0 = ald_f2(lp + jb + col);
      const float2 l1 = ald_f2(lp + jb + 16 + col);

      // shared h-part A-fragments (K rows 64..127), coherent loads
      bf16x8 aH[2][2];
      #pragma unroll
      for (int mt = 0; mt < 2; ++mt) {
        int jr = jb + mt * 16 + col;
        #pragma unroll
        for (int ks = 0; ks < 2; ++ks)
          aH[mt][ks] = ald_bf8(hbf_in + jr * 64 + ks * 32 + quad * 8);
      }

      #pragma unroll
      for (int ag = 0; ag < 2; ++ag) {
        const float2 li = ag ? liB : liA;
        const float d0x = l0.x - li.x, d0y = l0.y - li.y;
        const float d1x = l1.x - li.x, d1y = l1.y - li.y;

        bf16x8 aE[2][2];
        #pragma unroll
        for (int ks = 0; ks < 2; ++ks) {
          #pragma unroll
          for (int j = 0; j < 8; ++j) {
            float e0 = fmaxf(fmaf(d0y, wr1[ks][j], fmaf(d0x, wr0[ks][j], brl[ks][j])), 0.f);
            float e1 = fmaxf(fmaf(d1y, wr1[ks][j], fmaf(d1x, wr0[ks][j], brl[ks][j])), 0.f);
            aE[0][ks][j] = (__bf16)e0;
            aE[1][ks][j] = (__bf16)e1;
          }
        }

        f32x4 acc[2][4];
        #pragma unroll
        for (int mt = 0; mt < 2; ++mt)
          #pragma unroll
          for (int nt = 0; nt < 4; ++nt)
            acc[mt][nt] = (f32x4){0.f, 0.f, 0.f, 0.f};

        #pragma unroll
        for (int nt = 0; nt < 4; ++nt)
          #pragma unroll
          for (int mt = 0; mt < 2; ++mt) {
            acc[mt][nt] = __builtin_amdgcn_mfma_f32_16x16x32_bf16(aE[mt][0], bw[nt][0].v, acc[mt][nt], 0, 0, 0);
            acc[mt][nt] = __builtin_amdgcn_mfma_f32_16x16x32_bf16(aE[mt][1], bw[nt][1].v, acc[mt][nt], 0, 0, 0);
            acc[mt][nt] = __builtin_amdgcn_mfma_f32_16x16x32_bf16(aH[mt][0], bw[nt][2].v, acc[mt][nt], 0, 0, 0);
            acc[mt][nt] = __builtin_amdgcn_mfma_f32_16x16x32_bf16(aH[mt][1], bw[nt][3].v, acc[mt][nt], 0, 0, 0);
          }

        #pragma unroll
        for (int mt = 0; mt < 2; ++mt)
          #pragma unroll
          for (int nt = 0; nt < 4; ++nt)
            #pragma unroll
            for (int r = 0; r < 4; ++r) {
              float v = acc[mt][nt][r] + bp[nt];
              vmax[ag][nt] = fmaxf(fmaxf(v, 0.f), vmax[ag][nt]);
            }
      }
    }

    // reduce within wave, publish to LDS (per wave x per agent)
    #pragma unroll
    for (int ag = 0; ag < 2; ++ag)
      #pragma unroll
      for (int nt = 0; nt < 4; ++nt) {
        vmax[ag][nt] = fmaxf(vmax[ag][nt], __shfl_xor(vmax[ag][nt], 16, 64));
        vmax[ag][nt] = fmaxf(vmax[ag][nt], __shfl_xor(vmax[ag][nt], 32, 64));
      }
    if (lane < 16) {
      #pragma unroll
      for (int ag = 0; ag < 2; ++ag)
        #pragma unroll
        for (int nt = 0; nt < 4; ++nt)
          red[wave][ag][nt * 16 + lane] = vmax[ag][nt];
    }
    __syncthreads();

    // ---- head: wave 0 -> agent i0, wave 4 -> agent i0+1 ----
    if ((wave & 3) == 0) {
      const int ag = wave >> 2;
      const int i  = i0 + ag;
      const int o  = lane;
      float pooled = red[0][ag][o];
      #pragma unroll
      for (int w = 1; w < 8; ++w) pooled = fmaxf(pooled, red[w][ag][o]);

      float p0 = pooled * a.smallf[OFF_WPOS + o * 2 + 0];
      float p1 = pooled * a.smallf[OFF_WPOS + o * 2 + 1];
      #pragma unroll
      for (int sft = 32; sft >= 1; sft >>= 1) {
        p0 += __shfl_xor(p0, sft, 64);
        p1 += __shfl_xor(p1, sft, 64);
      }
      p0 += a.smallf[OFF_BPOS + 0];
      p1 += a.smallf[OFF_BPOS + 1];
      if (o == 0) {
        stout(a.out, i * 40 + (OBS + t) * 2 + 0, p0, isf32);   // plain; flushed at kernel end
        stout(a.out, i * 40 + (OBS + t) * 2 + 1, p1, isf32);
        union { unsigned long long q; float2 f; } u;
        u.f.x = p0; u.f.y = p1;
        ast64((unsigned long long*)(last_out + 2 * i), u.q);   // write-through
      }
      // GRU: lane o computes gate element o; h carried in registers
      float gir = 0.f, giz = 0.f, gin = 0.f, ghr = 0.f, ghz = 0.f, ghn = 0.f;
      #pragma unroll 8
      for (int k = 0; k < 64; ++k) {
        float ek = p0 * a.smallf[OFF_WEMB + k] + p1 * a.smallf[OFF_WEMB + 64 + k]
                 + a.smallf[OFF_BEMB + k];          // uniform
        float hk = __shfl(hreg, k, 64);             // uniform broadcast
        const float* w = a.WTf + k * 384;           // coalesced, L1/L2-cached
        gir += ek * w[o];
        giz += ek * w[64 + o];
        gin += ek * w[128 + o];
        ghr += hk * w[192 + o];
        ghz += hk * w[256 + o];
        ghn += hk * w[320 + o];
      }
      gir += a.smallf[OFF_BIH + o];       ghr += a.smallf[OFF_BHH + o];
      giz += a.smallf[OFF_BIH + 64 + o];  ghz += a.smallf[OFF_BHH + 64 + o];
      gin += a.smallf[OFF_BIH + 128 + o]; ghn += a.smallf[OFF_BHH + 128 + o];
      float r = 1.f / (1.f + __expf(-(gir + ghr)));
      float z = 1.f / (1.f + __expf(-(giz + ghz)));
      float n = tanhf(gin + r * ghn);
      float hn = (1.f - z) * n + z * hreg;
      hreg = hn;
      // publish bf16 h, packed in pairs, write-through
      unsigned short mybf = f2bf(hn);
      int part = __shfl_xor((int)mybf, 1, 64);
      if ((o & 1) == 0) {
        unsigned int pk = ((unsigned int)(part & 0xFFFF) << 16) | mybf;
        ast32((unsigned int*)(hbf_out + i * 64 + o), pk);
      }
    }

    if (t < PRE - 1) gbar(&a.cnts[1 + t], 256);
  }
}

// ===========================================================================
// R3 FALLBACK PATH (proven passing): prep + 12 pair kernels
// ===========================================================================
__global__ __launch_bounds__(64) void prep_kernel(
    const void* __restrict__ hidden_state, const void* __restrict__ group_track,
    const void* __restrict__ W_emb,  const void* __restrict__ b_emb,
    const void* __restrict__ W_ih,   const void* __restrict__ W_hh,
    const void* __restrict__ b_ih,   const void* __restrict__ b_hh,
    const void* __restrict__ W_pos,  const void* __restrict__ b_pos,
    const void* __restrict__ W_rel,  const void* __restrict__ b_rel,
    const void* __restrict__ W_pool, const void* __restrict__ b_pool,
    float* __restrict__ last0, unsigned short* __restrict__ hbf0,
    float* __restrict__ h_carry, float* __restrict__ WTf,
    unsigned short* __restrict__ Wp_bf, float* __restrict__ smallf,
    void* __restrict__ out)
{
  const int b = blockIdx.x;
  const int o = threadIdx.x;
  int bad = 0;
  const unsigned short* hs16 = (const unsigned short*)hidden_state;
  for (int k = o; k < 256; k += 64) {
    unsigned e = (hs16[k] >> 7) & 0xFFu;
    bad |= (e >= 0x8Eu) ? 1 : 0;
  }
  const bool isf32 = (__ballot(bad) != 0ULL);

  hbf0[b * 64 + o] = ld16(hidden_state, b * 64 + o, isf32);
  h_carry[b * 64 + o] = 0.0f;
  if (o < 16) stout(out, b * 40 + o, ldf(group_track, b * 16 + o, isf32), isf32);
  if (o < 2)  last0[b * 2 + o] = ldf(group_track, b * 16 + 14 + o, isf32);

  if (b < 384) {
    int u = b * 64 + o;
    int k = u / 384, c = u % 384;
    WTf[u] = (c < 192) ? ldf(W_ih, c * 64 + k, isf32)
                       : ldf(W_hh, (c - 192) * 64 + k, isf32);
  } else {
    int u = (b - 384) * 64 + o;
    Wp_bf[u] = ld16(W_pool, u, isf32);
  }
  if (b < 16) {
    int u = b * 64 + o;
    if (u < N_SMALL) {
      float v;
      if      (u < 128) v = ldf(W_rel,  u,        isf32);
      else if (u < 192) v = ldf(b_rel,  u - 128,  isf32);
      else if (u < 256) v = ldf(b_pool, u - 192,  isf32);
      else if (u < 384) v = ldf(W_pos,  u - 256,  isf32);
      else if (u < 386) v = ldf(b_pos,  u - 384,  isf32);
      else if (u < 514) v = ldf(W_emb,  u - 386,  isf32);
      else if (u < 578) v = ldf(b_emb,  u - 514,  isf32);
      else if (u < 770) v = ldf(b_ih,   u - 578,  isf32);
      else if (u < 962) v = ldf(b_hh,   u - 770,  isf32);
      else              v = isf32 ? 1.0f : 0.0f;
      smallf[u] = v;
    }
  }
}

__global__ __launch_bounds__(256) void pair_kernel(
    const float* __restrict__ smallf,
    const unsigned short* __restrict__ Wp_bf,
    const float* __restrict__ WTf,
    const float* __restrict__ last_in, float* __restrict__ last_out,
    const unsigned short* __restrict__ hbf_in, unsigned short* __restrict__ hbf_out,
    float* __restrict__ h_carry, void* __restrict__ out, int t)
{
  const int i    = blockIdx.x;
  const int tid  = threadIdx.x;
  const int lane = tid & 63;
  const int wave = tid >> 6;
  const int col  = lane & 15;
  const int quad = lane >> 4;

  __shared__ float red[4][64];

  const float2* lp = (const float2*)last_in;
  const float2  li = lp[i];

  float wr0[2][8], wr1[2][8], brl[2][8];
  #pragma unroll
  for (int ks = 0; ks < 2; ++ks) {
    int kb = ks * 32 + quad * 8;
    #pragma unroll
    for (int j = 0; j < 8; ++j) {
      wr0[ks][j] = smallf[OFF_WREL + kb + j];
      wr1[ks][j] = smallf[OFF_WREL + 64 + kb + j];
      brl[ks][j] = smallf[OFF_BREL + kb + j];
    }
  }
  float bp[4];
  #pragma unroll
  for (int nt = 0; nt < 4; ++nt) bp[nt] = smallf[OFF_BPOOL + nt * 16 + col];

  FragU bw[4][4];
  #pragma unroll
  for (int nt = 0; nt < 4; ++nt)
    #pragma unroll
    for (int ks = 0; ks < 4; ++ks)
      #pragma unroll
      for (int j = 0; j < 8; ++j)
        bw[nt][ks].u[j] = Wp_bf[(ks * 32 + quad * 8 + j) * 64 + nt * 16 + col];

  float vmax[4] = {0.f, 0.f, 0.f, 0.f};
  const int jb0 = wave * 128;
  for (int s = 0; s < 4; ++s) {
    const int jb = jb0 + s * 32;
    const float2 l0 = lp[jb + col], l1 = lp[jb + 16 + col];
    const float d0x = l0.x - li.x, d0y = l0.y - li.y;
    const float d1x = l1.x - li.x, d1y = l1.y - li.y;

    bf16x8 aE[2][2];
    #pragma unroll
    for (int ks = 0; ks < 2; ++ks)
      #pragma unroll
      for (int j = 0; j < 8; ++j) {
        float e0 = fmaxf(fmaf(d0y, wr1[ks][j], fmaf(d0x, wr0[ks][j], brl[ks][j])), 0.f);
        float e1 = fmaxf(fmaf(d1y, wr1[ks][j], fmaf(d1x, wr0[ks][j], brl[ks][j])), 0.f);
        aE[0][ks][j] = (__bf16)e0;
        aE[1][ks][j] = (__bf16)e1;
      }
    bf16x8 aH[2][2];
    #pragma unroll
    for (int mt = 0; mt < 2; ++mt) {
      int jr = jb + mt * 16 + col;
      #pragma unroll
      for (int ks = 0; ks < 2; ++ks)
        aH[mt][ks] = *(const bf16x8*)(hbf_in + jr * 64 + ks * 32 + quad * 8);
    }

    f32x4 acc[2][4];
    #pragma unroll
    for (int mt = 0; mt < 2; ++mt)
      #pragma unroll
      for (int nt = 0; nt < 4; ++nt)
        acc[mt][nt] = (f32x4){0.f, 0.f, 0.f, 0.f};

    #pragma unroll
    for (int nt = 0; nt < 4; ++nt)
      #pragma unroll
      for (int mt = 0; mt < 2; ++mt) {
        acc[mt][nt] = __builtin_amdgcn_mfma_f32_16x16x32_bf16(aE[mt][0], bw[nt][0].v, acc[mt][nt], 0, 0, 0);
        acc[mt][nt] = __builtin_amdgcn_mfma_f32_16x16x32_bf16(aE[mt][1], bw[nt][1].v, acc[mt][nt], 0, 0, 0);
        acc[mt][nt] = __builtin_amdgcn_mfma_f32_16x16x32_bf16(aH[mt][0], bw[nt][2].v, acc[mt][nt], 0, 0, 0);
        acc[mt][nt] = __builtin_amdgcn_mfma_f32_16x16x32_bf16(aH[mt][1], bw[nt][3].v, acc[mt][nt], 0, 0, 0);
      }

    #pragma unroll
    for (int mt = 0; mt < 2; ++mt)
      #pragma unroll
      for (int nt = 0; nt < 4; ++nt)
        #pragma unroll
        for (int r = 0; r < 4; ++r) {
          float v = acc[mt][nt][r] + bp[nt];
          vmax[nt] = fmaxf(fmaxf(v, 0.f), vmax[nt]);
        }
  }

  #pragma unroll
  for (int nt = 0; nt < 4; ++nt) {
    vmax[nt] = fmaxf(vmax[nt], __shfl_xor(vmax[nt], 16, 64));
    vmax[nt] = fmaxf(vmax[nt], __shfl_xor(vmax[nt], 32, 64));
  }
  if (lane < 16) {
    #pragma unroll
    for (int nt = 0; nt < 4; ++nt) red[wave][nt * 16 + lane] = vmax[nt];
  }
  __syncthreads();

  if (tid < 64) {
    const int o = tid;
    const bool isf32 = (smallf[OFF_FLAG] != 0.0f);
    float pooled = fmaxf(fmaxf(red[0][o], red[1][o]), fmaxf(red[2][o], red[3][o]));
    float p0 = pooled * smallf[OFF_WPOS + o * 2 + 0];
    float p1 = pooled * smallf[OFF_WPOS + o * 2 + 1];
    #pragma unroll
    for (int sft = 32; sft >= 1; sft >>= 1) {
      p0 += __shfl_xor(p0, sft, 64);
      p1 += __shfl_xor(p1, sft, 64);
    }
    p0 += smallf[OFF_BPOS + 0];
    p1 += smallf[OFF_BPOS + 1];
    if (o == 0) {
      stout(out, i * 40 + (OBS + t) * 2 + 0, p0, isf32);
      stout(out, i * 40 + (OBS + t) * 2 + 1, p1, isf32);
      last_out[2 * i]     = p0;
      last_out[2 * i + 1] = p1;
    }
    float gir = 0.f, giz = 0.f, gin = 0.f, ghr = 0.f, ghz = 0.f, ghn = 0.f;
    #pragma unroll 8
    for (int k = 0; k < 64; ++k) {
      float ek = p0 * smallf[OFF_WEMB + k] + p1 * smallf[OFF_WEMB + 64 + k]
               + smallf[OFF_BEMB + k];
      float hk = h_carry[i * 64 + k];
      const float* w = WTf + k * 384;
      gir += ek * w[o];
      giz += ek * w[64 + o];
      gin += ek * w[128 + o];
      ghr += hk * w[192 + o];
      ghz += hk * w[256 + o];
      ghn += hk * w[320 + o];
    }
    gir += smallf[OFF_BIH + o];       ghr += smallf[OFF_BHH + o];
    giz += smallf[OFF_BIH + 64 + o];  ghz += smallf[OFF_BHH + 64 + o];
    gin += smallf[OFF_BIH + 128 + o]; ghn += smallf[OFF_BHH + 128 + o];
    float r = 1.f / (1.f + __expf(-(gir + ghr)));
    float z = 1.f / (1.f + __expf(-(giz + ghz)));
    float n = tanhf(gin + r * ghn);
    float hp = h_carry[i * 64 + o];
    float hn = (1.f - z) * n + z * hp;
    h_carry[i * 64 + o] = hn;
    hbf_out[i * 64 + o] = f2bf(hn);
  }
}

// ---------------------------------------------------------------------------
extern "C" void kernel_launch(void* const* d_in, const int* in_sizes, int n_in,
                              void* d_out, int out_size, void* d_ws, size_t ws_size,
                              hipStream_t stream) {
  (void)in_sizes; (void)n_in; (void)out_size; (void)ws_size;
  const void* hidden_state = d_in[0];
  const void* group_track  = d_in[1];
  const void* W_emb  = d_in[2];
  const void* b_emb  = d_in[3];
  const void* W_ih   = d_in[4];
  const void* W_hh   = d_in[5];
  const void* b_ih   = d_in[6];
  const void* b_hh   = d_in[7];
  const void* W_pos  = d_in[8];
  const void* b_pos  = d_in[9];
  const void* W_rel  = d_in[10];
  const void* b_rel  = d_in[11];
  const void* W_pool = d_in[12];
  const void* b_pool = d_in[13];

  char* ws = (char*)d_ws;
  float* last[2]          = {(float*)(ws + 0),      (float*)(ws + 4096)};
  unsigned short* hbf[2]  = {(unsigned short*)(ws + 8192),
                             (unsigned short*)(ws + 73728)};
  float* h_carry          = (float*)(ws + 139264);          // fallback path only
  float* WTf              = (float*)(ws + 270336);          // 98304 B
  unsigned short* Wp_bf   = (unsigned short*)(ws + 368640); // 16384 B
  float* smallf           = (float*)(ws + 385024);          // ~3856 B
  unsigned int* cnts      = (unsigned int*)(ws + 401408);   // 13 barrier counters

  // zero the barrier counters (graph-capturable async memset)
  hipMemsetAsync(cnts, 0, 64, stream);

  FusedArgs fa;
  fa.hidden_state = hidden_state; fa.group_track = group_track;
  fa.W_emb = W_emb; fa.b_emb = b_emb; fa.W_ih = W_ih; fa.W_hh = W_hh;
  fa.b_ih = b_ih; fa.b_hh = b_hh; fa.W_pos = W_pos; fa.b_pos = b_pos;
  fa.W_rel = W_rel; fa.b_rel = b_rel; fa.W_pool = W_pool; fa.b_pool = b_pool;
  fa.last0 = last[0]; fa.last1 = last[1];
  fa.hbf0 = hbf[0]; fa.hbf1 = hbf[1];
  fa.WTf = WTf; fa.Wp_bf = Wp_bf; fa.smallf = smallf;
  fa.cnts = cnts; fa.out = d_out;

  void* params[] = { &fa };
  hipError_t err = hipLaunchCooperativeKernel((const void*)fused_kernel,
                                              dim3(256), dim3(512),
                                              params, 0, stream);
  if (err != hipSuccess) {
    // Fallback: proven 13-kernel path (identical math)
    prep_kernel<<<512, 64, 0, stream>>>(hidden_state, group_track,
                                        W_emb, b_emb, W_ih, W_hh, b_ih, b_hh,
                                        W_pos, b_pos, W_rel, b_rel, W_pool, b_pool,
                                        last[0], hbf[0], h_carry, WTf, Wp_bf,
                                        smallf, d_out);
    for (int t = 0; t < PRE; ++t) {
      int p = t & 1;
      pair_kernel<<<512, 256, 0, stream>>>(smallf, Wp_bf, WTf,
                                           last[p], last[1 - p],
                                           hbf[p], hbf[1 - p],
                                           h_carry, d_out, t);
    }
  }
}

// Round 7
// 288.954 us; speedup vs baseline: 1.9135x; 1.1640x over previous
//
#include <hip/hip_runtime.h>
#include <math.h>

// Problem constants
#define NB   512   // B
#define NH   64    // H = E = HP
#define OBS  8
#define PRE  12

// small f32 param pack offsets (elements)
#define OFF_WREL  0     // 128
#define OFF_BREL  128   // 64
#define OFF_BPOOL 192   // 64
#define OFF_WPOS  256   // 128
#define OFF_BPOS  384   // 2
#define OFF_WEMB  386   // 128
#define OFF_BEMB  514   // 64
#define OFF_BIH   578   // 192
#define OFF_BHH   770   // 192
#define OFF_FLAG  962   // 1: 1.0 if buffers are f32, 0.0 if bf16
#define N_SMALL   963

typedef __bf16 bf16x8 __attribute__((ext_vector_type(8)));
typedef float  f32x4  __attribute__((ext_vector_type(4)));
typedef float  f32x2  __attribute__((ext_vector_type(2)));

union FragU { bf16x8 v; unsigned short u[8]; };

__device__ __forceinline__ float bf2f(unsigned short u) {
  unsigned int x = ((unsigned int)u) << 16;
  return __builtin_bit_cast(float, x);
}
__device__ __forceinline__ unsigned short f2bf(float f) {
  unsigned int u = __builtin_bit_cast(unsigned int, f);
  u += 0x7FFFu + ((u >> 16) & 1u);   // RNE
  return (unsigned short)(u >> 16);
}
__device__ __forceinline__ float ldf(const void* p, int i, bool isf32) {
  return isf32 ? ((const float*)p)[i] : bf2f(((const unsigned short*)p)[i]);
}
__device__ __forceinline__ unsigned short ld16(const void* p, int i, bool isf32) {
  return isf32 ? f2bf(((const float*)p)[i]) : ((const unsigned short*)p)[i];
}
__device__ __forceinline__ void stout(void* p, int i, float v, bool isf32) {
  if (isf32) ((float*)p)[i] = v;
  else       ((unsigned short*)p)[i] = f2bf(v);
}

// ---- write-through (coherence-point) stores: relaxed agent atomics
__device__ __forceinline__ void ast32(unsigned int* p, unsigned int v) {
  __hip_atomic_store(p, v, __ATOMIC_RELAXED, __HIP_MEMORY_SCOPE_AGENT);
}
__device__ __forceinline__ void ast64(unsigned long long* p, unsigned long long v) {
  __hip_atomic_store(p, v, __ATOMIC_RELAXED, __HIP_MEMORY_SCOPE_AGENT);
}

// ---- wide cache-bypass loads (sc0 sc1: no L1/L2 hit or allocate) ----------
// 8x16B aH loads issued WITHOUT waitcnt (overlapped with e-gen).
__device__ __forceinline__ void issue_aH(const unsigned short* b0, const unsigned short* b1,
    bf16x8* h00, bf16x8* h01, bf16x8* h02, bf16x8* h03,
    bf16x8* h10, bf16x8* h11, bf16x8* h12, bf16x8* h13) {
  asm volatile(
    "global_load_dwordx4 %0, %8, off sc0 sc1\n\t"
    "global_load_dwordx4 %1, %8, off offset:64 sc0 sc1\n\t"
    "global_load_dwordx4 %2, %8, off offset:2048 sc0 sc1\n\t"
    "global_load_dwordx4 %3, %8, off offset:2112 sc0 sc1\n\t"
    "global_load_dwordx4 %4, %9, off sc0 sc1\n\t"
    "global_load_dwordx4 %5, %9, off offset:64 sc0 sc1\n\t"
    "global_load_dwordx4 %6, %9, off offset:2048 sc0 sc1\n\t"
    "global_load_dwordx4 %7, %9, off offset:2112 sc0 sc1"
    : "=&v"(*h00), "=&v"(*h01), "=&v"(*h02), "=&v"(*h03),
      "=&v"(*h10), "=&v"(*h11), "=&v"(*h12), "=&v"(*h13)
    : "v"(b0), "v"(b1)
    : "memory");
}
__device__ __forceinline__ void wait_aH(bf16x8* a, bf16x8* b, bf16x8* c, bf16x8* d,
                                        bf16x8* e, bf16x8* f, bf16x8* g, bf16x8* h) {
  asm volatile("s_waitcnt vmcnt(0)"
    : "+v"(*a), "+v"(*b), "+v"(*c), "+v"(*d),
      "+v"(*e), "+v"(*f), "+v"(*g), "+v"(*h)
    :: "memory");
}
// 6x8B last-position loads, blocking (one waitcnt for all).
__device__ __forceinline__ void ld_last6(const float2* qi, const float2* qj,
    f32x2* li0, f32x2* li1, f32x2* l00, f32x2* l10, f32x2* l01, f32x2* l11) {
  asm volatile(
    "global_load_dwordx2 %0, %6, off sc0 sc1\n\t"
    "global_load_dwordx2 %1, %6, off offset:8 sc0 sc1\n\t"
    "global_load_dwordx2 %2, %7, off sc0 sc1\n\t"
    "global_load_dwordx2 %3, %7, off offset:128 sc0 sc1\n\t"
    "global_load_dwordx2 %4, %7, off offset:256 sc0 sc1\n\t"
    "global_load_dwordx2 %5, %7, off offset:384 sc0 sc1\n\t"
    "s_waitcnt vmcnt(0)"
    : "=&v"(*li0), "=&v"(*li1), "=&v"(*l00), "=&v"(*l10), "=&v"(*l01), "=&v"(*l11)
    : "v"(qi), "v"(qj)
    : "memory");
}

// ---------------------------------------------------------------------------
// Fence-free grid barrier v3: busy-wait (no s_sleep — bypass-load RT is the
// backoff), last arriver broadcasts to 8 spread release flags (32 pollers per
// line). All cross-block data is write-through / cache-bypass, so no cache
// maintenance is needed. Requires 256 co-resident blocks (cooperative launch).
// ---------------------------------------------------------------------------
__device__ __forceinline__ void gbar(unsigned int* cnt, unsigned int* flg) {
  __builtin_amdgcn_s_waitcnt(0);     // this wave's stores ack'd at coherence point
  __syncthreads();
  if (threadIdx.x == 0) {
    unsigned old = __hip_atomic_fetch_add(cnt, 1u, __ATOMIC_RELAXED,
                                          __HIP_MEMORY_SCOPE_AGENT);
    if (old == 255u) {
      #pragma unroll
      for (int x = 0; x < 8; ++x)
        __hip_atomic_store(flg + x * 32, 1u, __ATOMIC_RELAXED,
                           __HIP_MEMORY_SCOPE_AGENT);
    } else {
      const unsigned int* f = flg + (blockIdx.x & 7) * 32;
      while (__hip_atomic_load(f, __ATOMIC_RELAXED,
                               __HIP_MEMORY_SCOPE_AGENT) == 0u) { }
    }
  }
  __syncthreads();
}

// ===========================================================================
// FUSED cooperative kernel: prep + 12 decoder iterations
// grid: 256 blocks x 512 threads. Block handles agents i0=2*bid, i1=2*bid+1.
// Wave w covers j-rows [w*64,(w+1)*64) for BOTH agents (shares aH loads).
// ===========================================================================
struct FusedArgs {
  const void *hidden_state, *group_track, *W_emb, *b_emb, *W_ih, *W_hh,
             *b_ih, *b_hh, *W_pos, *b_pos, *W_rel, *b_rel, *W_pool, *b_pool;
  float *last0, *last1;
  unsigned short *hbf0, *hbf1;
  float *WTf;
  unsigned short *Wp_bf;
  float *smallf;
  unsigned int *cnts;    // [16] counters + 13 x 256 flag words, pre-zeroed
  void *out;
};

__global__ __launch_bounds__(512, 2) void fused_kernel(FusedArgs a)
{
  const int tid  = threadIdx.x;
  const int lane = tid & 63;
  const int wave = tid >> 6;
  const int col  = lane & 15;   // MFMA m/n index
  const int quad = lane >> 4;   // k-group selector
  const int gid  = blockIdx.x * 512 + tid;
  const int i0   = 2 * blockIdx.x;

  __shared__ float red[8][2][64];

  // ---- dtype detect (per wave, uniform) ----
  int bad = 0;
  const unsigned short* hs16 = (const unsigned short*)a.hidden_state;
  for (int k = lane; k < 256; k += 64) {
    unsigned e = (hs16[k] >> 7) & 0xFFu;
    bad |= (e >= 0x8Eu) ? 1 : 0;
  }
  const bool isf32 = (__ballot(bad) != 0ULL);

  // ---- prep: canonicalize inputs into ws via write-through stores ----
  if (gid < 16384) {                        // hbf0: 16384 uint pairs
    unsigned int pk = ((unsigned int)ld16(a.hidden_state, 2 * gid + 1, isf32) << 16)
                    | ld16(a.hidden_state, 2 * gid, isf32);
    ast32((unsigned int*)a.hbf0 + gid, pk);
  } else if (gid < 16896) {                 // last0: 512 agents, 8B each
    int g = gid - 16384;
    union { unsigned long long q; float2 f; } u;
    u.f.x = ldf(a.group_track, g * 16 + 14, isf32);
    u.f.y = ldf(a.group_track, g * 16 + 15, isf32);
    ast64((unsigned long long*)(a.last0 + 2 * g), u.q);
  } else if (gid < 25088) {                 // out[:, :8, :] copy (plain stores)
    int g = gid - 16896;
    int i = g >> 4, o = g & 15;
    stout(a.out, i * 40 + o, ldf(a.group_track, i * 16 + o, isf32), isf32);
  } else if (gid >= 32768 && gid < 57344) { // transposed GRU weights (24576 f32)
    int u = gid - 32768;
    int k = u / 384, c = u % 384;
    float v = (c < 192) ? ldf(a.W_ih, c * 64 + k, isf32)
                        : ldf(a.W_hh, (c - 192) * 64 + k, isf32);
    ast32((unsigned int*)(a.WTf + u), __builtin_bit_cast(unsigned int, v));
  } else if (gid >= 57344 && gid < 61440) { // bf16 W_pool: 4096 uint pairs
    int u = gid - 57344;
    unsigned int pk = ((unsigned int)ld16(a.W_pool, 2 * u + 1, isf32) << 16)
                    | ld16(a.W_pool, 2 * u, isf32);
    ast32((unsigned int*)a.Wp_bf + u, pk);
  } else if (gid >= 61440 && gid < 61440 + N_SMALL) {  // small param pack
    int u = gid - 61440;
    float v;
    if      (u < 128) v = ldf(a.W_rel,  u,        isf32);
    else if (u < 192) v = ldf(a.b_rel,  u - 128,  isf32);
    else if (u < 256) v = ldf(a.b_pool, u - 192,  isf32);
    else if (u < 384) v = ldf(a.W_pos,  u - 256,  isf32);
    else if (u < 386) v = ldf(a.b_pos,  u - 384,  isf32);
    else if (u < 514) v = ldf(a.W_emb,  u - 386,  isf32);
    else if (u < 578) v = ldf(a.b_emb,  u - 514,  isf32);
    else if (u < 770) v = ldf(a.b_ih,   u - 578,  isf32);
    else if (u < 962) v = ldf(a.b_hh,   u - 770,  isf32);
    else              v = isf32 ? 1.0f : 0.0f;
    ast32((unsigned int*)(a.smallf + u), __builtin_bit_cast(unsigned int, v));
  }

  gbar(&a.cnts[0], a.cnts + 16);   // ws canonical; weights plain-cacheable (never re-written)

  // ---- loop-invariant weights into registers ONCE (plain cached loads) ----
  float wr0[2][8], wr1[2][8], brl[2][8];
  #pragma unroll
  for (int ks = 0; ks < 2; ++ks) {
    int kb = ks * 32 + quad * 8;
    #pragma unroll
    for (int j = 0; j < 8; ++j) {
      wr0[ks][j] = a.smallf[OFF_WREL + kb + j];
      wr1[ks][j] = a.smallf[OFF_WREL + 64 + kb + j];
      brl[ks][j] = a.smallf[OFF_BREL + kb + j];
    }
  }
  float bp[4];
  #pragma unroll
  for (int nt = 0; nt < 4; ++nt) bp[nt] = a.smallf[OFF_BPOOL + nt * 16 + col];

  FragU bw[4][4];   // B-fragments of W_pool: B[ks*32+quad*8+j][nt*16+col]
  #pragma unroll
  for (int nt = 0; nt < 4; ++nt)
    #pragma unroll
    for (int ks = 0; ks < 4; ++ks)
      #pragma unroll
      for (int j = 0; j < 8; ++j)
        bw[nt][ks].u[j] = a.Wp_bf[(ks * 32 + quad * 8 + j) * 64 + nt * 16 + col];

  const int jb0 = wave * 64;   // this wave's j-range (64 rows, both agents)
  float hreg = 0.0f;           // GRU carry (head waves 0 and 4)

  // ---- 12 decoder iterations ----
  for (int t = 0; t < PRE; ++t) {
    const int p = t & 1;
    const float* last_in  = p ? a.last1 : a.last0;
    float*       last_out = p ? a.last0 : a.last1;
    const unsigned short* hbf_in  = p ? a.hbf1 : a.hbf0;
    unsigned short*       hbf_out = p ? a.hbf0 : a.hbf1;

    const float2* lp = (const float2*)last_in;

    // issue 8x16B aH bypass loads (no wait yet)
    const unsigned short* hb0 = hbf_in + (jb0 + col) * 64 + quad * 8;
    bf16x8 h00, h01, h02, h03, h10, h11, h12, h13;
    issue_aH(hb0, hb0 + 2048, &h00, &h01, &h02, &h03, &h10, &h11, &h12, &h13);

    // 6x8B last loads, blocking (waits everything incl. aH — one RT total)
    f32x2 li0, li1, l0s[2], l1s[2];
    ld_last6(lp + i0, lp + jb0 + col, &li0, &li1, &l0s[0], &l1s[0], &l0s[1], &l1s[1]);

    float vmax[2][4] = {{0.f,0.f,0.f,0.f},{0.f,0.f,0.f,0.f}};

    #pragma unroll
    for (int s = 0; s < 2; ++s) {
      bf16x8 aH00 = s ? h10 : h00, aH01 = s ? h11 : h01;
      bf16x8 aH10 = s ? h12 : h02, aH11 = s ? h13 : h03;

      #pragma unroll
      for (int ag = 0; ag < 2; ++ag) {
        const f32x2 li = ag ? li1 : li0;
        const float d0x = l0s[s][0] - li[0], d0y = l0s[s][1] - li[1];
        const float d1x = l1s[s][0] - li[0], d1y = l1s[s][1] - li[1];

        bf16x8 aE[2][2];
        #pragma unroll
        for (int ks = 0; ks < 2; ++ks) {
          #pragma unroll
          for (int j = 0; j < 8; ++j) {
            float e0 = fmaxf(fmaf(d0y, wr1[ks][j], fmaf(d0x, wr0[ks][j], brl[ks][j])), 0.f);
            float e1 = fmaxf(fmaf(d1y, wr1[ks][j], fmaf(d1x, wr0[ks][j], brl[ks][j])), 0.f);
            aE[0][ks][j] = (__bf16)e0;
            aE[1][ks][j] = (__bf16)e1;
          }
        }
        if (s == 0 && ag == 0)
          wait_aH(&h00, &h01, &h02, &h03, &h10, &h11, &h12, &h13);

        f32x4 acc[2][4];
        #pragma unroll
        for (int mt = 0; mt < 2; ++mt)
          #pragma unroll
          for (int nt = 0; nt < 4; ++nt)
            acc[mt][nt] = (f32x4){0.f, 0.f, 0.f, 0.f};

        #pragma unroll
        for (int nt = 0; nt < 4; ++nt)
          #pragma unroll
          for (int mt = 0; mt < 2; ++mt) {
            acc[mt][nt] = __builtin_amdgcn_mfma_f32_16x16x32_bf16(aE[mt][0], bw[nt][0].v, acc[mt][nt], 0, 0, 0);
            acc[mt][nt] = __builtin_amdgcn_mfma_f32_16x16x32_bf16(aE[mt][1], bw[nt][1].v, acc[mt][nt], 0, 0, 0);
            acc[mt][nt] = __builtin_amdgcn_mfma_f32_16x16x32_bf16(mt ? aH10 : aH00, bw[nt][2].v, acc[mt][nt], 0, 0, 0);
            acc[mt][nt] = __builtin_amdgcn_mfma_f32_16x16x32_bf16(mt ? aH11 : aH01, bw[nt][3].v, acc[mt][nt], 0, 0, 0);
          }

        #pragma unroll
        for (int mt = 0; mt < 2; ++mt)
          #pragma unroll
          for (int nt = 0; nt < 4; ++nt)
            #pragma unroll
            for (int r = 0; r < 4; ++r) {
              float v = acc[mt][nt][r] + bp[nt];
              vmax[ag][nt] = fmaxf(fmaxf(v, 0.f), vmax[ag][nt]);
            }
      }
    }

    // reduce within wave, publish to LDS (per wave x per agent)
    #pragma unroll
    for (int ag = 0; ag < 2; ++ag)
      #pragma unroll
      for (int nt = 0; nt < 4; ++nt) {
        vmax[ag][nt] = fmaxf(vmax[ag][nt], __shfl_xor(vmax[ag][nt], 16, 64));
        vmax[ag][nt] = fmaxf(vmax[ag][nt], __shfl_xor(vmax[ag][nt], 32, 64));
      }
    if (lane < 16) {
      #pragma unroll
      for (int ag = 0; ag < 2; ++ag)
        #pragma unroll
        for (int nt = 0; nt < 4; ++nt)
          red[wave][ag][nt * 16 + lane] = vmax[ag][nt];
    }
    __syncthreads();

    // ---- head: wave 0 -> agent i0, wave 4 -> agent i0+1 ----
    if ((wave & 3) == 0) {
      const int ag = wave >> 2;
      const int i  = i0 + ag;
      const int o  = lane;
      float pooled = red[0][ag][o];
      #pragma unroll
      for (int w = 1; w < 8; ++w) pooled = fmaxf(pooled, red[w][ag][o]);

      float p0 = pooled * a.smallf[OFF_WPOS + o * 2 + 0];
      float p1 = pooled * a.smallf[OFF_WPOS + o * 2 + 1];
      #pragma unroll
      for (int sft = 32; sft >= 1; sft >>= 1) {
        p0 += __shfl_xor(p0, sft, 64);
        p1 += __shfl_xor(p1, sft, 64);
      }
      p0 += a.smallf[OFF_BPOS + 0];
      p1 += a.smallf[OFF_BPOS + 1];
      if (o == 0) {
        stout(a.out, i * 40 + (OBS + t) * 2 + 0, p0, isf32);   // plain; flushed at kernel end
        stout(a.out, i * 40 + (OBS + t) * 2 + 1, p1, isf32);
        union { unsigned long long q; float2 f; } u;
        u.f.x = p0; u.f.y = p1;
        ast64((unsigned long long*)(last_out + 2 * i), u.q);   // write-through
      }
      // GRU: lane o computes gate element o; h carried in registers
      float gir = 0.f, giz = 0.f, gin = 0.f, ghr = 0.f, ghz = 0.f, ghn = 0.f;
      #pragma unroll 8
      for (int k = 0; k < 64; ++k) {
        float ek = p0 * a.smallf[OFF_WEMB + k] + p1 * a.smallf[OFF_WEMB + 64 + k]
                 + a.smallf[OFF_BEMB + k];          // uniform
        float hk = __shfl(hreg, k, 64);             // uniform broadcast
        const float* w = a.WTf + k * 384;           // coalesced, L2-cached
        gir += ek * w[o];
        giz += ek * w[64 + o];
        gin += ek * w[128 + o];
        ghr += hk * w[192 + o];
        ghz += hk * w[256 + o];
        ghn += hk * w[320 + o];
      }
      gir += a.smallf[OFF_BIH + o];       ghr += a.smallf[OFF_BHH + o];
      giz += a.smallf[OFF_BIH + 64 + o];  ghz += a.smallf[OFF_BHH + 64 + o];
      gin += a.smallf[OFF_BIH + 128 + o]; ghn += a.smallf[OFF_BHH + 128 + o];
      float r = 1.f / (1.f + __expf(-(gir + ghr)));
      float z = 1.f / (1.f + __expf(-(giz + ghz)));
      float n = tanhf(gin + r * ghn);
      float hn = (1.f - z) * n + z * hreg;
      hreg = hn;
      // publish bf16 h, packed in pairs, write-through
      unsigned short mybf = f2bf(hn);
      int part = __shfl_xor((int)mybf, 1, 64);
      if ((o & 1) == 0) {
        unsigned int pk = ((unsigned int)(part & 0xFFFF) << 16) | mybf;
        ast32((unsigned int*)(hbf_out + i * 64 + o), pk);
      }
    }

    if (t < PRE - 1) gbar(&a.cnts[1 + t], a.cnts + 16 + (1 + t) * 256);
  }
}

// ===========================================================================
// R3 FALLBACK PATH (proven passing): prep + 12 pair kernels
// ===========================================================================
__global__ __launch_bounds__(64) void prep_kernel(
    const void* __restrict__ hidden_state, const void* __restrict__ group_track,
    const void* __restrict__ W_emb,  const void* __restrict__ b_emb,
    const void* __restrict__ W_ih,   const void* __restrict__ W_hh,
    const void* __restrict__ b_ih,   const void* __restrict__ b_hh,
    const void* __restrict__ W_pos,  const void* __restrict__ b_pos,
    const void* __restrict__ W_rel,  const void* __restrict__ b_rel,
    const void* __restrict__ W_pool, const void* __restrict__ b_pool,
    float* __restrict__ last0, unsigned short* __restrict__ hbf0,
    float* __restrict__ h_carry, float* __restrict__ WTf,
    unsigned short* __restrict__ Wp_bf, float* __restrict__ smallf,
    void* __restrict__ out)
{
  const int b = blockIdx.x;
  const int o = threadIdx.x;
  int bad = 0;
  const unsigned short* hs16 = (const unsigned short*)hidden_state;
  for (int k = o; k < 256; k += 64) {
    unsigned e = (hs16[k] >> 7) & 0xFFu;
    bad |= (e >= 0x8Eu) ? 1 : 0;
  }
  const bool isf32 = (__ballot(bad) != 0ULL);

  hbf0[b * 64 + o] = ld16(hidden_state, b * 64 + o, isf32);
  h_carry[b * 64 + o] = 0.0f;
  if (o < 16) stout(out, b * 40 + o, ldf(group_track, b * 16 + o, isf32), isf32);
  if (o < 2)  last0[b * 2 + o] = ldf(group_track, b * 16 + 14 + o, isf32);

  if (b < 384) {
    int u = b * 64 + o;
    int k = u / 384, c = u % 384;
    WTf[u] = (c < 192) ? ldf(W_ih, c * 64 + k, isf32)
                       : ldf(W_hh, (c - 192) * 64 + k, isf32);
  } else {
    int u = (b - 384) * 64 + o;
    Wp_bf[u] = ld16(W_pool, u, isf32);
  }
  if (b < 16) {
    int u = b * 64 + o;
    if (u < N_SMALL) {
      float v;
      if      (u < 128) v = ldf(W_rel,  u,        isf32);
      else if (u < 192) v = ldf(b_rel,  u - 128,  isf32);
      else if (u < 256) v = ldf(b_pool, u - 192,  isf32);
      else if (u < 384) v = ldf(W_pos,  u - 256,  isf32);
      else if (u < 386) v = ldf(b_pos,  u - 384,  isf32);
      else if (u < 514) v = ldf(W_emb,  u - 386,  isf32);
      else if (u < 578) v = ldf(b_emb,  u - 514,  isf32);
      else if (u < 770) v = ldf(b_ih,   u - 578,  isf32);
      else if (u < 962) v = ldf(b_hh,   u - 770,  isf32);
      else              v = isf32 ? 1.0f : 0.0f;
      smallf[u] = v;
    }
  }
}

__global__ __launch_bounds__(256) void pair_kernel(
    const float* __restrict__ smallf,
    const unsigned short* __restrict__ Wp_bf,
    const float* __restrict__ WTf,
    const float* __restrict__ last_in, float* __restrict__ last_out,
    const unsigned short* __restrict__ hbf_in, unsigned short* __restrict__ hbf_out,
    float* __restrict__ h_carry, void* __restrict__ out, int t)
{
  const int i    = blockIdx.x;
  const int tid  = threadIdx.x;
  const int lane = tid & 63;
  const int wave = tid >> 6;
  const int col  = lane & 15;
  const int quad = lane >> 4;

  __shared__ float red[4][64];

  const float2* lp = (const float2*)last_in;
  const float2  li = lp[i];

  float wr0[2][8], wr1[2][8], brl[2][8];
  #pragma unroll
  for (int ks = 0; ks < 2; ++ks) {
    int kb = ks * 32 + quad * 8;
    #pragma unroll
    for (int j = 0; j < 8; ++j) {
      wr0[ks][j] = smallf[OFF_WREL + kb + j];
      wr1[ks][j] = smallf[OFF_WREL + 64 + kb + j];
      brl[ks][j] = smallf[OFF_BREL + kb + j];
    }
  }
  float bp[4];
  #pragma unroll
  for (int nt = 0; nt < 4; ++nt) bp[nt] = smallf[OFF_BPOOL + nt * 16 + col];

  FragU bw[4][4];
  #pragma unroll
  for (int nt = 0; nt < 4; ++nt)
    #pragma unroll
    for (int ks = 0; ks < 4; ++ks)
      #pragma unroll
      for (int j = 0; j < 8; ++j)
        bw[nt][ks].u[j] = Wp_bf[(ks * 32 + quad * 8 + j) * 64 + nt * 16 + col];

  float vmax[4] = {0.f, 0.f, 0.f, 0.f};
  const int jb0 = wave * 128;
  for (int s = 0; s < 4; ++s) {
    const int jb = jb0 + s * 32;
    const float2 l0 = lp[jb + col], l1 = lp[jb + 16 + col];
    const float d0x = l0.x - li.x, d0y = l0.y - li.y;
    const float d1x = l1.x - li.x, d1y = l1.y - li.y;

    bf16x8 aE[2][2];
    #pragma unroll
    for (int ks = 0; ks < 2; ++ks)
      #pragma unroll
      for (int j = 0; j < 8; ++j) {
        float e0 = fmaxf(fmaf(d0y, wr1[ks][j], fmaf(d0x, wr0[ks][j], brl[ks][j])), 0.f);
        float e1 = fmaxf(fmaf(d1y, wr1[ks][j], fmaf(d1x, wr0[ks][j], brl[ks][j])), 0.f);
        aE[0][ks][j] = (__bf16)e0;
        aE[1][ks][j] = (__bf16)e1;
      }
    bf16x8 aH[2][2];
    #pragma unroll
    for (int mt = 0; mt < 2; ++mt) {
      int jr = jb + mt * 16 + col;
      #pragma unroll
      for (int ks = 0; ks < 2; ++ks)
        aH[mt][ks] = *(const bf16x8*)(hbf_in + jr * 64 + ks * 32 + quad * 8);
    }

    f32x4 acc[2][4];
    #pragma unroll
    for (int mt = 0; mt < 2; ++mt)
      #pragma unroll
      for (int nt = 0; nt < 4; ++nt)
        acc[mt][nt] = (f32x4){0.f, 0.f, 0.f, 0.f};

    #pragma unroll
    for (int nt = 0; nt < 4; ++nt)
      #pragma unroll
      for (int mt = 0; mt < 2; ++mt) {
        acc[mt][nt] = __builtin_amdgcn_mfma_f32_16x16x32_bf16(aE[mt][0], bw[nt][0].v, acc[mt][nt], 0, 0, 0);
        acc[mt][nt] = __builtin_amdgcn_mfma_f32_16x16x32_bf16(aE[mt][1], bw[nt][1].v, acc[mt][nt], 0, 0, 0);
        acc[mt][nt] = __builtin_amdgcn_mfma_f32_16x16x32_bf16(aH[mt][0], bw[nt][2].v, acc[mt][nt], 0, 0, 0);
        acc[mt][nt] = __builtin_amdgcn_mfma_f32_16x16x32_bf16(aH[mt][1], bw[nt][3].v, acc[mt][nt], 0, 0, 0);
      }

    #pragma unroll
    for (int mt = 0; mt < 2; ++mt)
      #pragma unroll
      for (int nt = 0; nt < 4; ++nt)
        #pragma unroll
        for (int r = 0; r < 4; ++r) {
          float v = acc[mt][nt][r] + bp[nt];
          vmax[nt] = fmaxf(fmaxf(v, 0.f), vmax[nt]);
        }
  }

  #pragma unroll
  for (int nt = 0; nt < 4; ++nt) {
    vmax[nt] = fmaxf(vmax[nt], __shfl_xor(vmax[nt], 16, 64));
    vmax[nt] = fmaxf(vmax[nt], __shfl_xor(vmax[nt], 32, 64));
  }
  if (lane < 16) {
    #pragma unroll
    for (int nt = 0; nt < 4; ++nt) red[wave][nt * 16 + lane] = vmax[nt];
  }
  __syncthreads();

  if (tid < 64) {
    const int o = tid;
    const bool isf32 = (smallf[OFF_FLAG] != 0.0f);
    float pooled = fmaxf(fmaxf(red[0][o], red[1][o]), fmaxf(red[2][o], red[3][o]));
    float p0 = pooled * smallf[OFF_WPOS + o * 2 + 0];
    float p1 = pooled * smallf[OFF_WPOS + o * 2 + 1];
    #pragma unroll
    for (int sft = 32; sft >= 1; sft >>= 1) {
      p0 += __shfl_xor(p0, sft, 64);
      p1 += __shfl_xor(p1, sft, 64);
    }
    p0 += smallf[OFF_BPOS + 0];
    p1 += smallf[OFF_BPOS + 1];
    if (o == 0) {
      stout(out, i * 40 + (OBS + t) * 2 + 0, p0, isf32);
      stout(out, i * 40 + (OBS + t) * 2 + 1, p1, isf32);
      last_out[2 * i]     = p0;
      last_out[2 * i + 1] = p1;
    }
    float gir = 0.f, giz = 0.f, gin = 0.f, ghr = 0.f, ghz = 0.f, ghn = 0.f;
    #pragma unroll 8
    for (int k = 0; k < 64; ++k) {
      float ek = p0 * smallf[OFF_WEMB + k] + p1 * smallf[OFF_WEMB + 64 + k]
               + smallf[OFF_BEMB + k];
      float hk = h_carry[i * 64 + k];
      const float* w = WTf + k * 384;
      gir += ek * w[o];
      giz += ek * w[64 + o];
      gin += ek * w[128 + o];
      ghr += hk * w[192 + o];
      ghz += hk * w[256 + o];
      ghn += hk * w[320 + o];
    }
    gir += smallf[OFF_BIH + o];       ghr += smallf[OFF_BHH + o];
    giz += smallf[OFF_BIH + 64 + o];  ghz += smallf[OFF_BHH + 64 + o];
    gin += smallf[OFF_BIH + 128 + o]; ghn += smallf[OFF_BHH + 128 + o];
    float r = 1.f / (1.f + __expf(-(gir + ghr)));
    float z = 1.f / (1.f + __expf(-(giz + ghz)));
    float n = tanhf(gin + r * ghn);
    float hp = h_carry[i * 64 + o];
    float hn = (1.f - z) * n + z * hp;
    h_carry[i * 64 + o] = hn;
    hbf_out[i * 64 + o] = f2bf(hn);
  }
}

// ---------------------------------------------------------------------------
extern "C" void kernel_launch(void* const* d_in, const int* in_sizes, int n_in,
                              void* d_out, int out_size, void* d_ws, size_t ws_size,
                              hipStream_t stream) {
  (void)in_sizes; (void)n_in; (void)out_size; (void)ws_size;
  const void* hidden_state = d_in[0];
  const void* group_track  = d_in[1];
  const void* W_emb  = d_in[2];
  const void* b_emb  = d_in[3];
  const void* W_ih   = d_in[4];
  const void* W_hh   = d_in[5];
  const void* b_ih   = d_in[6];
  const void* b_hh   = d_in[7];
  const void* W_pos  = d_in[8];
  const void* b_pos  = d_in[9];
  const void* W_rel  = d_in[10];
  const void* b_rel  = d_in[11];
  const void* W_pool = d_in[12];
  const void* b_pool = d_in[13];

  char* ws = (char*)d_ws;
  float* last[2]          = {(float*)(ws + 0),      (float*)(ws + 4096)};
  unsigned short* hbf[2]  = {(unsigned short*)(ws + 8192),
                             (unsigned short*)(ws + 73728)};
  float* h_carry          = (float*)(ws + 139264);          // fallback path only
  float* WTf              = (float*)(ws + 270336);          // 98304 B
  unsigned short* Wp_bf   = (unsigned short*)(ws + 368640); // 16384 B
  float* smallf           = (float*)(ws + 385024);          // ~3856 B
  unsigned int* cnts      = (unsigned int*)(ws + 401408);   // counters + flags

  // zero counters + release flags (16 + 13*256 u32 = 13376 B)
  hipMemsetAsync(cnts, 0, 16384, stream);

  FusedArgs fa;
  fa.hidden_state = hidden_state; fa.group_track = group_track;
  fa.W_emb = W_emb; fa.b_emb = b_emb; fa.W_ih = W_ih; fa.W_hh = W_hh;
  fa.b_ih = b_ih; fa.b_hh = b_hh; fa.W_pos = W_pos; fa.b_pos = b_pos;
  fa.W_rel = W_rel; fa.b_rel = b_rel; fa.W_pool = W_pool; fa.b_pool = b_pool;
  fa.last0 = last[0]; fa.last1 = last[1];
  fa.hbf0 = hbf[0]; fa.hbf1 = hbf[1];
  fa.WTf = WTf; fa.Wp_bf = Wp_bf; fa.smallf = smallf;
  fa.cnts = cnts; fa.out = d_out;

  void* params[] = { &fa };
  hipError_t err = hipLaunchCooperativeKernel((const void*)fused_kernel,
                                              dim3(256), dim3(512),
                                              params, 0, stream);
  if (err != hipSuccess) {
    // Fallback: proven 13-kernel path (identical math)
    prep_kernel<<<512, 64, 0, stream>>>(hidden_state, group_track,
                                        W_emb, b_emb, W_ih, W_hh, b_ih, b_hh,
                                        W_pos, b_pos, W_rel, b_rel, W_pool, b_pool,
                                        last[0], hbf[0], h_carry, WTf, Wp_bf,
                                        smallf, d_out);
    for (int t = 0; t < PRE; ++t) {
      int p = t & 1;
      pair_kernel<<<512, 256, 0, stream>>>(smallf, Wp_bf, WTf,
                                           last[p], last[1 - p],
                                           hbf[p], hbf[1 - p],
                                           h_carry, d_out, t);
    }
  }
}

// Round 8
// 279.997 us; speedup vs baseline: 1.9747x; 1.0320x over previous
//
#include <hip/hip_runtime.h>
#include <math.h>

// Problem constants
#define NB   512   // B
#define NH   64    // H = E = HP
#define OBS  8
#define PRE  12

// small f32 param pack offsets (elements)
#define OFF_WREL  0     // 128
#define OFF_BREL  128   // 64
#define OFF_BPOOL 192   // 64
#define OFF_WPOS  256   // 128
#define OFF_BPOS  384   // 2
#define OFF_WEMB  386   // 128
#define OFF_BEMB  514   // 64
#define OFF_BIH   578   // 192
#define OFF_BHH   770   // 192
#define OFF_FLAG  962   // 1: 1.0 if buffers are f32, 0.0 if bf16
#define N_SMALL   963

typedef __bf16 bf16x8 __attribute__((ext_vector_type(8)));
typedef float  f32x4  __attribute__((ext_vector_type(4)));

union FragU { bf16x8 v; unsigned short u[8]; };

__device__ __forceinline__ float bf2f(unsigned short u) {
  unsigned int x = ((unsigned int)u) << 16;
  return __builtin_bit_cast(float, x);
}
__device__ __forceinline__ unsigned short f2bf(float f) {
  unsigned int u = __builtin_bit_cast(unsigned int, f);
  u += 0x7FFFu + ((u >> 16) & 1u);   // RNE
  return (unsigned short)(u >> 16);
}
__device__ __forceinline__ float ldf(const void* p, int i, bool isf32) {
  return isf32 ? ((const float*)p)[i] : bf2f(((const unsigned short*)p)[i]);
}
__device__ __forceinline__ unsigned short ld16(const void* p, int i, bool isf32) {
  return isf32 ? f2bf(((const float*)p)[i]) : ((const unsigned short*)p)[i];
}
__device__ __forceinline__ void stout(void* p, int i, float v, bool isf32) {
  if (isf32) ((float*)p)[i] = v;
  else       ((unsigned short*)p)[i] = f2bf(v);
}

// ---- write-through (coherence-point) stores: relaxed agent atomics
__device__ __forceinline__ void ast32(unsigned int* p, unsigned int v) {
  __hip_atomic_store(p, v, __ATOMIC_RELAXED, __HIP_MEMORY_SCOPE_AGENT);
}
__device__ __forceinline__ void ast64(unsigned long long* p, unsigned long long v) {
  __hip_atomic_store(p, v, __ATOMIC_RELAXED, __HIP_MEMORY_SCOPE_AGENT);
}

// ---------------------------------------------------------------------------
// Fence-free grid barrier (R7-proven): busy-wait, last arriver broadcasts to
// 8 spread release flags. Data protocol: producers write cross-block state
// via write-through atomic stores; s_waitcnt(0) acks them at the MALL before
// arrival, so flag observation implies data visibility. Consumers read via
// PLAIN loads into per-iteration ROTATING buffers whose addresses are L2-cold
// (never read earlier this launch; kernel-launch acquire invalidates L2 —
// empirically validated by R6/R7 plain reads of WTf across poisoned replays).
// ---------------------------------------------------------------------------
__device__ __forceinline__ void gbar(unsigned int* cnt, unsigned int* flg) {
  __builtin_amdgcn_s_waitcnt(0);
  __syncthreads();
  if (threadIdx.x == 0) {
    unsigned old = __hip_atomic_fetch_add(cnt, 1u, __ATOMIC_RELAXED,
                                          __HIP_MEMORY_SCOPE_AGENT);
    if (old == 255u) {
      #pragma unroll
      for (int x = 0; x < 8; ++x)
        __hip_atomic_store(flg + x * 32, 1u, __ATOMIC_RELAXED,
                           __HIP_MEMORY_SCOPE_AGENT);
    } else {
      const unsigned int* f = flg + (blockIdx.x & 7) * 32;
      while (__hip_atomic_load(f, __ATOMIC_RELAXED,
                               __HIP_MEMORY_SCOPE_AGENT) == 0u) { }
    }
  }
  __syncthreads();
}

// ===========================================================================
// FUSED cooperative kernel: prep + 12 decoder iterations
// grid: 256 blocks x 512 threads. Block handles agents i0=2*bid, i1=2*bid+1.
// Wave w covers j-rows [w*64,(w+1)*64) for BOTH agents (shares aH loads).
// State buffers rotate per iteration: read hbf[t]/last[t], write [t+1].
// ===========================================================================
struct FusedArgs {
  const void *hidden_state, *group_track, *W_emb, *b_emb, *W_ih, *W_hh,
             *b_ih, *b_hh, *W_pos, *b_pos, *W_rel, *b_rel, *W_pool, *b_pool;
  unsigned short *hbfs;  // 13 x 32768 bf16 (65536 B each)
  float *lasts;          // 13 x 1024 f32 (4096 B each)
  float *WTf;
  unsigned short *Wp_bf;
  float *smallf;
  unsigned int *cnts;    // [16] counters + 13 x 256 flag words, pre-zeroed
  void *out;
};

__global__ __launch_bounds__(512, 2) void fused_kernel(FusedArgs a)
{
  const int tid  = threadIdx.x;
  const int lane = tid & 63;
  const int wave = tid >> 6;
  const int col  = lane & 15;   // MFMA m/n index
  const int quad = lane >> 4;   // k-group selector
  const int gid  = blockIdx.x * 512 + tid;
  const int i0   = 2 * blockIdx.x;

  __shared__ float red[8][2][64];

  // ---- dtype detect (per wave, uniform) ----
  int bad = 0;
  const unsigned short* hs16 = (const unsigned short*)a.hidden_state;
  for (int k = lane; k < 256; k += 64) {
    unsigned e = (hs16[k] >> 7) & 0xFFu;
    bad |= (e >= 0x8Eu) ? 1 : 0;
  }
  const bool isf32 = (__ballot(bad) != 0ULL);

  // ---- prep: canonicalize inputs into ws via write-through stores ----
  if (gid < 16384) {                        // hbf[0]: 16384 uint pairs
    unsigned int pk = ((unsigned int)ld16(a.hidden_state, 2 * gid + 1, isf32) << 16)
                    | ld16(a.hidden_state, 2 * gid, isf32);
    ast32((unsigned int*)a.hbfs + gid, pk);
  } else if (gid < 16896) {                 // last[0]: 512 agents, 8B each
    int g = gid - 16384;
    union { unsigned long long q; float2 f; } u;
    u.f.x = ldf(a.group_track, g * 16 + 14, isf32);
    u.f.y = ldf(a.group_track, g * 16 + 15, isf32);
    ast64((unsigned long long*)(a.lasts + 2 * g), u.q);
  } else if (gid < 25088) {                 // out[:, :8, :] copy (plain stores)
    int g = gid - 16896;
    int i = g >> 4, o = g & 15;
    stout(a.out, i * 40 + o, ldf(a.group_track, i * 16 + o, isf32), isf32);
  } else if (gid >= 32768 && gid < 57344) { // transposed GRU weights (24576 f32)
    int u = gid - 32768;
    int k = u / 384, c = u % 384;
    float v = (c < 192) ? ldf(a.W_ih, c * 64 + k, isf32)
                        : ldf(a.W_hh, (c - 192) * 64 + k, isf32);
    ast32((unsigned int*)(a.WTf + u), __builtin_bit_cast(unsigned int, v));
  } else if (gid >= 57344 && gid < 61440) { // bf16 W_pool: 4096 uint pairs
    int u = gid - 57344;
    unsigned int pk = ((unsigned int)ld16(a.W_pool, 2 * u + 1, isf32) << 16)
                    | ld16(a.W_pool, 2 * u, isf32);
    ast32((unsigned int*)a.Wp_bf + u, pk);
  } else if (gid >= 61440 && gid < 61440 + N_SMALL) {  // small param pack
    int u = gid - 61440;
    float v;
    if      (u < 128) v = ldf(a.W_rel,  u,        isf32);
    else if (u < 192) v = ldf(a.b_rel,  u - 128,  isf32);
    else if (u < 256) v = ldf(a.b_pool, u - 192,  isf32);
    else if (u < 384) v = ldf(a.W_pos,  u - 256,  isf32);
    else if (u < 386) v = ldf(a.b_pos,  u - 384,  isf32);
    else if (u < 514) v = ldf(a.W_emb,  u - 386,  isf32);
    else if (u < 578) v = ldf(a.b_emb,  u - 514,  isf32);
    else if (u < 770) v = ldf(a.b_ih,   u - 578,  isf32);
    else if (u < 962) v = ldf(a.b_hh,   u - 770,  isf32);
    else              v = isf32 ? 1.0f : 0.0f;
    ast32((unsigned int*)(a.smallf + u), __builtin_bit_cast(unsigned int, v));
  }

  gbar(&a.cnts[0], a.cnts + 16);   // ws canonical; everything plain-cacheable now

  // ---- loop-invariant weights into registers ONCE (plain cached loads) ----
  float wr0[2][8], wr1[2][8], brl[2][8];
  #pragma unroll
  for (int ks = 0; ks < 2; ++ks) {
    int kb = ks * 32 + quad * 8;
    #pragma unroll
    for (int j = 0; j < 8; ++j) {
      wr0[ks][j] = a.smallf[OFF_WREL + kb + j];
      wr1[ks][j] = a.smallf[OFF_WREL + 64 + kb + j];
      brl[ks][j] = a.smallf[OFF_BREL + kb + j];
    }
  }
  float bp[4];
  #pragma unroll
  for (int nt = 0; nt < 4; ++nt) bp[nt] = a.smallf[OFF_BPOOL + nt * 16 + col];

  FragU bw[4][4];   // B-fragments of W_pool: B[ks*32+quad*8+j][nt*16+col]
  #pragma unroll
  for (int nt = 0; nt < 4; ++nt)
    #pragma unroll
    for (int ks = 0; ks < 4; ++ks)
      #pragma unroll
      for (int j = 0; j < 8; ++j)
        bw[nt][ks].u[j] = a.Wp_bf[(ks * 32 + quad * 8 + j) * 64 + nt * 16 + col];

  const int jb0 = wave * 64;   // this wave's j-range (64 rows, both agents)
  float hreg = 0.0f;           // GRU carry (head waves 0 and 4)

  // ---- 12 decoder iterations ----
  for (int t = 0; t < PRE; ++t) {
    const unsigned short* hbf_in  = a.hbfs + t * 32768;
    unsigned short*       hbf_out = a.hbfs + (t + 1) * 32768;
    const float*          last_in = a.lasts + t * 1024;
    float*                last_out= a.lasts + (t + 1) * 1024;

    const float2* lp = (const float2*)last_in;

    // plain cached loads: first toucher per XCD fills L2 from MALL, rest hit
    const unsigned short* hb0 = hbf_in + (jb0 + col) * 64 + quad * 8;
    bf16x8 h00 = *(const bf16x8*)(hb0);            // row r,     k 0..31 half
    bf16x8 h01 = *(const bf16x8*)(hb0 + 32);       // row r,     k 32..63 half
    bf16x8 h02 = *(const bf16x8*)(hb0 + 1024);     // row r+16
    bf16x8 h03 = *(const bf16x8*)(hb0 + 1056);
    bf16x8 h10 = *(const bf16x8*)(hb0 + 2048);     // row r+32
    bf16x8 h11 = *(const bf16x8*)(hb0 + 2080);
    bf16x8 h12 = *(const bf16x8*)(hb0 + 3072);     // row r+48
    bf16x8 h13 = *(const bf16x8*)(hb0 + 3104);

    const float2 li0 = lp[i0], li1 = lp[i0 + 1];
    float2 l0s[2], l1s[2];
    #pragma unroll
    for (int s = 0; s < 2; ++s) {
      l0s[s] = lp[jb0 + s * 32 + col];
      l1s[s] = lp[jb0 + s * 32 + 16 + col];
    }

    float vmax[2][4] = {{0.f,0.f,0.f,0.f},{0.f,0.f,0.f,0.f}};

    #pragma unroll
    for (int s = 0; s < 2; ++s) {
      bf16x8 aH00 = s ? h10 : h00, aH01 = s ? h11 : h01;
      bf16x8 aH10 = s ? h12 : h02, aH11 = s ? h13 : h03;

      #pragma unroll
      for (int ag = 0; ag < 2; ++ag) {
        const float2 li = ag ? li1 : li0;
        const float d0x = l0s[s].x - li.x, d0y = l0s[s].y - li.y;
        const float d1x = l1s[s].x - li.x, d1y = l1s[s].y - li.y;

        bf16x8 aE[2][2];
        #pragma unroll
        for (int ks = 0; ks < 2; ++ks) {
          #pragma unroll
          for (int j = 0; j < 8; ++j) {
            float e0 = fmaxf(fmaf(d0y, wr1[ks][j], fmaf(d0x, wr0[ks][j], brl[ks][j])), 0.f);
            float e1 = fmaxf(fmaf(d1y, wr1[ks][j], fmaf(d1x, wr0[ks][j], brl[ks][j])), 0.f);
            aE[0][ks][j] = (__bf16)e0;
            aE[1][ks][j] = (__bf16)e1;
          }
        }

        f32x4 acc[2][4];
        #pragma unroll
        for (int mt = 0; mt < 2; ++mt)
          #pragma unroll
          for (int nt = 0; nt < 4; ++nt)
            acc[mt][nt] = (f32x4){0.f, 0.f, 0.f, 0.f};

        #pragma unroll
        for (int nt = 0; nt < 4; ++nt)
          #pragma unroll
          for (int mt = 0; mt < 2; ++mt) {
            acc[mt][nt] = __builtin_amdgcn_mfma_f32_16x16x32_bf16(aE[mt][0], bw[nt][0].v, acc[mt][nt], 0, 0, 0);
            acc[mt][nt] = __builtin_amdgcn_mfma_f32_16x16x32_bf16(aE[mt][1], bw[nt][1].v, acc[mt][nt], 0, 0, 0);
            acc[mt][nt] = __builtin_amdgcn_mfma_f32_16x16x32_bf16(mt ? aH10 : aH00, bw[nt][2].v, acc[mt][nt], 0, 0, 0);
            acc[mt][nt] = __builtin_amdgcn_mfma_f32_16x16x32_bf16(mt ? aH11 : aH01, bw[nt][3].v, acc[mt][nt], 0, 0, 0);
          }

        #pragma unroll
        for (int mt = 0; mt < 2; ++mt)
          #pragma unroll
          for (int nt = 0; nt < 4; ++nt)
            #pragma unroll
            for (int r = 0; r < 4; ++r) {
              float v = acc[mt][nt][r] + bp[nt];
              vmax[ag][nt] = fmaxf(fmaxf(v, 0.f), vmax[ag][nt]);
            }
      }
    }

    // reduce within wave, publish to LDS (per wave x per agent)
    #pragma unroll
    for (int ag = 0; ag < 2; ++ag)
      #pragma unroll
      for (int nt = 0; nt < 4; ++nt) {
        vmax[ag][nt] = fmaxf(vmax[ag][nt], __shfl_xor(vmax[ag][nt], 16, 64));
        vmax[ag][nt] = fmaxf(vmax[ag][nt], __shfl_xor(vmax[ag][nt], 32, 64));
      }
    if (lane < 16) {
      #pragma unroll
      for (int ag = 0; ag < 2; ++ag)
        #pragma unroll
        for (int nt = 0; nt < 4; ++nt)
          red[wave][ag][nt * 16 + lane] = vmax[ag][nt];
    }
    __syncthreads();

    // ---- head: wave 0 -> agent i0, wave 4 -> agent i0+1 ----
    if ((wave & 3) == 0) {
      const int ag = wave >> 2;
      const int i  = i0 + ag;
      const int o  = lane;
      float pooled = red[0][ag][o];
      #pragma unroll
      for (int w = 1; w < 8; ++w) pooled = fmaxf(pooled, red[w][ag][o]);

      float p0 = pooled * a.smallf[OFF_WPOS + o * 2 + 0];
      float p1 = pooled * a.smallf[OFF_WPOS + o * 2 + 1];
      #pragma unroll
      for (int sft = 32; sft >= 1; sft >>= 1) {
        p0 += __shfl_xor(p0, sft, 64);
        p1 += __shfl_xor(p1, sft, 64);
      }
      p0 += a.smallf[OFF_BPOS + 0];
      p1 += a.smallf[OFF_BPOS + 1];
      if (o == 0) {
        stout(a.out, i * 40 + (OBS + t) * 2 + 0, p0, isf32);   // plain; flushed at kernel end
        stout(a.out, i * 40 + (OBS + t) * 2 + 1, p1, isf32);
        union { unsigned long long q; float2 f; } u;
        u.f.x = p0; u.f.y = p1;
        ast64((unsigned long long*)(last_out + 2 * i), u.q);   // write-through
      }
      // GRU: lane o computes gate element o; h carried in registers
      float gir = 0.f, giz = 0.f, gin = 0.f, ghr = 0.f, ghz = 0.f, ghn = 0.f;
      #pragma unroll 8
      for (int k = 0; k < 64; ++k) {
        float ek = p0 * a.smallf[OFF_WEMB + k] + p1 * a.smallf[OFF_WEMB + 64 + k]
                 + a.smallf[OFF_BEMB + k];          // uniform
        float hk = __shfl(hreg, k, 64);             // uniform broadcast
        const float* w = a.WTf + k * 384;           // coalesced, L2-cached
        gir += ek * w[o];
        giz += ek * w[64 + o];
        gin += ek * w[128 + o];
        ghr += hk * w[192 + o];
        ghz += hk * w[256 + o];
        ghn += hk * w[320 + o];
      }
      gir += a.smallf[OFF_BIH + o];       ghr += a.smallf[OFF_BHH + o];
      giz += a.smallf[OFF_BIH + 64 + o];  ghz += a.smallf[OFF_BHH + 64 + o];
      gin += a.smallf[OFF_BIH + 128 + o]; ghn += a.smallf[OFF_BHH + 128 + o];
      float r = 1.f / (1.f + __expf(-(gir + ghr)));
      float z = 1.f / (1.f + __expf(-(giz + ghz)));
      float n = tanhf(gin + r * ghn);
      float hn = (1.f - z) * n + z * hreg;
      hreg = hn;
      // publish bf16 h into NEXT iteration's buffer, write-through
      unsigned short mybf = f2bf(hn);
      int part = __shfl_xor((int)mybf, 1, 64);
      if ((o & 1) == 0) {
        unsigned int pk = ((unsigned int)(part & 0xFFFF) << 16) | mybf;
        ast32((unsigned int*)(hbf_out + i * 64 + o), pk);
      }
    }

    if (t < PRE - 1) gbar(&a.cnts[1 + t], a.cnts + 16 + (1 + t) * 256);
  }
}

// ===========================================================================
// R3 FALLBACK PATH (proven passing): prep + 12 pair kernels
// ===========================================================================
__global__ __launch_bounds__(64) void prep_kernel(
    const void* __restrict__ hidden_state, const void* __restrict__ group_track,
    const void* __restrict__ W_emb,  const void* __restrict__ b_emb,
    const void* __restrict__ W_ih,   const void* __restrict__ W_hh,
    const void* __restrict__ b_ih,   const void* __restrict__ b_hh,
    const void* __restrict__ W_pos,  const void* __restrict__ b_pos,
    const void* __restrict__ W_rel,  const void* __restrict__ b_rel,
    const void* __restrict__ W_pool, const void* __restrict__ b_pool,
    float* __restrict__ last0, unsigned short* __restrict__ hbf0,
    float* __restrict__ h_carry, float* __restrict__ WTf,
    unsigned short* __restrict__ Wp_bf, float* __restrict__ smallf,
    void* __restrict__ out)
{
  const int b = blockIdx.x;
  const int o = threadIdx.x;
  int bad = 0;
  const unsigned short* hs16 = (const unsigned short*)hidden_state;
  for (int k = o; k < 256; k += 64) {
    unsigned e = (hs16[k] >> 7) & 0xFFu;
    bad |= (e >= 0x8Eu) ? 1 : 0;
  }
  const bool isf32 = (__ballot(bad) != 0ULL);

  hbf0[b * 64 + o] = ld16(hidden_state, b * 64 + o, isf32);
  h_carry[b * 64 + o] = 0.0f;
  if (o < 16) stout(out, b * 40 + o, ldf(group_track, b * 16 + o, isf32), isf32);
  if (o < 2)  last0[b * 2 + o] = ldf(group_track, b * 16 + 14 + o, isf32);

  if (b < 384) {
    int u = b * 64 + o;
    int k = u / 384, c = u % 384;
    WTf[u] = (c < 192) ? ldf(W_ih, c * 64 + k, isf32)
                       : ldf(W_hh, (c - 192) * 64 + k, isf32);
  } else {
    int u = (b - 384) * 64 + o;
    Wp_bf[u] = ld16(W_pool, u, isf32);
  }
  if (b < 16) {
    int u = b * 64 + o;
    if (u < N_SMALL) {
      float v;
      if      (u < 128) v = ldf(W_rel,  u,        isf32);
      else if (u < 192) v = ldf(b_rel,  u - 128,  isf32);
      else if (u < 256) v = ldf(b_pool, u - 192,  isf32);
      else if (u < 384) v = ldf(W_pos,  u - 256,  isf32);
      else if (u < 386) v = ldf(b_pos,  u - 384,  isf32);
      else if (u < 514) v = ldf(W_emb,  u - 386,  isf32);
      else if (u < 578) v = ldf(b_emb,  u - 514,  isf32);
      else if (u < 770) v = ldf(b_ih,   u - 578,  isf32);
      else if (u < 962) v = ldf(b_hh,   u - 770,  isf32);
      else              v = isf32 ? 1.0f : 0.0f;
      smallf[u] = v;
    }
  }
}

__global__ __launch_bounds__(256) void pair_kernel(
    const float* __restrict__ smallf,
    const unsigned short* __restrict__ Wp_bf,
    const float* __restrict__ WTf,
    const float* __restrict__ last_in, float* __restrict__ last_out,
    const unsigned short* __restrict__ hbf_in, unsigned short* __restrict__ hbf_out,
    float* __restrict__ h_carry, void* __restrict__ out, int t)
{
  const int i    = blockIdx.x;
  const int tid  = threadIdx.x;
  const int lane = tid & 63;
  const int wave = tid >> 6;
  const int col  = lane & 15;
  const int quad = lane >> 4;

  __shared__ float red[4][64];

  const float2* lp = (const float2*)last_in;
  const float2  li = lp[i];

  float wr0[2][8], wr1[2][8], brl[2][8];
  #pragma unroll
  for (int ks = 0; ks < 2; ++ks) {
    int kb = ks * 32 + quad * 8;
    #pragma unroll
    for (int j = 0; j < 8; ++j) {
      wr0[ks][j] = smallf[OFF_WREL + kb + j];
      wr1[ks][j] = smallf[OFF_WREL + 64 + kb + j];
      brl[ks][j] = smallf[OFF_BREL + kb + j];
    }
  }
  float bp[4];
  #pragma unroll
  for (int nt = 0; nt < 4; ++nt) bp[nt] = smallf[OFF_BPOOL + nt * 16 + col];

  FragU bw[4][4];
  #pragma unroll
  for (int nt = 0; nt < 4; ++nt)
    #pragma unroll
    for (int ks = 0; ks < 4; ++ks)
      #pragma unroll
      for (int j = 0; j < 8; ++j)
        bw[nt][ks].u[j] = Wp_bf[(ks * 32 + quad * 8 + j) * 64 + nt * 16 + col];

  float vmax[4] = {0.f, 0.f, 0.f, 0.f};
  const int jb0 = wave * 128;
  for (int s = 0; s < 4; ++s) {
    const int jb = jb0 + s * 32;
    const float2 l0 = lp[jb + col], l1 = lp[jb + 16 + col];
    const float d0x = l0.x - li.x, d0y = l0.y - li.y;
    const float d1x = l1.x - li.x, d1y = l1.y - li.y;

    bf16x8 aE[2][2];
    #pragma unroll
    for (int ks = 0; ks < 2; ++ks)
      #pragma unroll
      for (int j = 0; j < 8; ++j) {
        float e0 = fmaxf(fmaf(d0y, wr1[ks][j], fmaf(d0x, wr0[ks][j], brl[ks][j])), 0.f);
        float e1 = fmaxf(fmaf(d1y, wr1[ks][j], fmaf(d1x, wr0[ks][j], brl[ks][j])), 0.f);
        aE[0][ks][j] = (__bf16)e0;
        aE[1][ks][j] = (__bf16)e1;
      }
    bf16x8 aH[2][2];
    #pragma unroll
    for (int mt = 0; mt < 2; ++mt) {
      int jr = jb + mt * 16 + col;
      #pragma unroll
      for (int ks = 0; ks < 2; ++ks)
        aH[mt][ks] = *(const bf16x8*)(hbf_in + jr * 64 + ks * 32 + quad * 8);
    }

    f32x4 acc[2][4];
    #pragma unroll
    for (int mt = 0; mt < 2; ++mt)
      #pragma unroll
      for (int nt = 0; nt < 4; ++nt)
        acc[mt][nt] = (f32x4){0.f, 0.f, 0.f, 0.f};

    #pragma unroll
    for (int nt = 0; nt < 4; ++nt)
      #pragma unroll
      for (int mt = 0; mt < 2; ++mt) {
        acc[mt][nt] = __builtin_amdgcn_mfma_f32_16x16x32_bf16(aE[mt][0], bw[nt][0].v, acc[mt][nt], 0, 0, 0);
        acc[mt][nt] = __builtin_amdgcn_mfma_f32_16x16x32_bf16(aE[mt][1], bw[nt][1].v, acc[mt][nt], 0, 0, 0);
        acc[mt][nt] = __builtin_amdgcn_mfma_f32_16x16x32_bf16(aH[mt][0], bw[nt][2].v, acc[mt][nt], 0, 0, 0);
        acc[mt][nt] = __builtin_amdgcn_mfma_f32_16x16x32_bf16(aH[mt][1], bw[nt][3].v, acc[mt][nt], 0, 0, 0);
      }

    #pragma unroll
    for (int mt = 0; mt < 2; ++mt)
      #pragma unroll
      for (int nt = 0; nt < 4; ++nt)
        #pragma unroll
        for (int r = 0; r < 4; ++r) {
          float v = acc[mt][nt][r] + bp[nt];
          vmax[nt] = fmaxf(fmaxf(v, 0.f), vmax[nt]);
        }
  }

  #pragma unroll
  for (int nt = 0; nt < 4; ++nt) {
    vmax[nt] = fmaxf(vmax[nt], __shfl_xor(vmax[nt], 16, 64));
    vmax[nt] = fmaxf(vmax[nt], __shfl_xor(vmax[nt], 32, 64));
  }
  if (lane < 16) {
    #pragma unroll
    for (int nt = 0; nt < 4; ++nt) red[wave][nt * 16 + lane] = vmax[nt];
  }
  __syncthreads();

  if (tid < 64) {
    const int o = tid;
    const bool isf32 = (smallf[OFF_FLAG] != 0.0f);
    float pooled = fmaxf(fmaxf(red[0][o], red[1][o]), fmaxf(red[2][o], red[3][o]));
    float p0 = pooled * smallf[OFF_WPOS + o * 2 + 0];
    float p1 = pooled * smallf[OFF_WPOS + o * 2 + 1];
    #pragma unroll
    for (int sft = 32; sft >= 1; sft >>= 1) {
      p0 += __shfl_xor(p0, sft, 64);
      p1 += __shfl_xor(p1, sft, 64);
    }
    p0 += smallf[OFF_BPOS + 0];
    p1 += smallf[OFF_BPOS + 1];
    if (o == 0) {
      stout(out, i * 40 + (OBS + t) * 2 + 0, p0, isf32);
      stout(out, i * 40 + (OBS + t) * 2 + 1, p1, isf32);
      last_out[2 * i]     = p0;
      last_out[2 * i + 1] = p1;
    }
    float gir = 0.f, giz = 0.f, gin = 0.f, ghr = 0.f, ghz = 0.f, ghn = 0.f;
    #pragma unroll 8
    for (int k = 0; k < 64; ++k) {
      float ek = p0 * smallf[OFF_WEMB + k] + p1 * smallf[OFF_WEMB + 64 + k]
               + smallf[OFF_BEMB + k];
      float hk = h_carry[i * 64 + k];
      const float* w = WTf + k * 384;
      gir += ek * w[o];
      giz += ek * w[64 + o];
      gin += ek * w[128 + o];
      ghr += hk * w[192 + o];
      ghz += hk * w[256 + o];
      ghn += hk * w[320 + o];
    }
    gir += smallf[OFF_BIH + o];       ghr += smallf[OFF_BHH + o];
    giz += smallf[OFF_BIH + 64 + o];  ghz += smallf[OFF_BHH + 64 + o];
    gin += smallf[OFF_BIH + 128 + o]; ghn += smallf[OFF_BHH + 128 + o];
    float r = 1.f / (1.f + __expf(-(gir + ghr)));
    float z = 1.f / (1.f + __expf(-(giz + ghz)));
    float n = tanhf(gin + r * ghn);
    float hp = h_carry[i * 64 + o];
    float hn = (1.f - z) * n + z * hp;
    h_carry[i * 64 + o] = hn;
    hbf_out[i * 64 + o] = f2bf(hn);
  }
}

// ---------------------------------------------------------------------------
extern "C" void kernel_launch(void* const* d_in, const int* in_sizes, int n_in,
                              void* d_out, int out_size, void* d_ws, size_t ws_size,
                              hipStream_t stream) {
  (void)in_sizes; (void)n_in; (void)out_size; (void)ws_size;
  const void* hidden_state = d_in[0];
  const void* group_track  = d_in[1];
  const void* W_emb  = d_in[2];
  const void* b_emb  = d_in[3];
  const void* W_ih   = d_in[4];
  const void* W_hh   = d_in[5];
  const void* b_ih   = d_in[6];
  const void* b_hh   = d_in[7];
  const void* W_pos  = d_in[8];
  const void* b_pos  = d_in[9];
  const void* W_rel  = d_in[10];
  const void* b_rel  = d_in[11];
  const void* W_pool = d_in[12];
  const void* b_pool = d_in[13];

  char* ws = (char*)d_ws;
  // rotating state: 13 hbf buffers (64 KB each) + 13 last buffers (4 KB each)
  unsigned short* hbfs    = (unsigned short*)(ws + 0);        // [0, 851968)
  float* lasts            = (float*)(ws + 851968);            // [851968, 905216)
  float* WTf              = (float*)(ws + 905216);            // 98304 B
  unsigned short* Wp_bf   = (unsigned short*)(ws + 1003520);  // 16384 B
  float* smallf           = (float*)(ws + 1019904);           // ~3856 B
  unsigned int* cnts      = (unsigned int*)(ws + 1024000);    // 16384 B
  float* h_carry          = (float*)(ws + 1048576);           // fallback only

  // zero counters + release flags
  hipMemsetAsync(cnts, 0, 16384, stream);

  FusedArgs fa;
  fa.hidden_state = hidden_state; fa.group_track = group_track;
  fa.W_emb = W_emb; fa.b_emb = b_emb; fa.W_ih = W_ih; fa.W_hh = W_hh;
  fa.b_ih = b_ih; fa.b_hh = b_hh; fa.W_pos = W_pos; fa.b_pos = b_pos;
  fa.W_rel = W_rel; fa.b_rel = b_rel; fa.W_pool = W_pool; fa.b_pool = b_pool;
  fa.hbfs = hbfs; fa.lasts = lasts;
  fa.WTf = WTf; fa.Wp_bf = Wp_bf; fa.smallf = smallf;
  fa.cnts = cnts; fa.out = d_out;

  void* params[] = { &fa };
  hipError_t err = hipLaunchCooperativeKernel((const void*)fused_kernel,
                                              dim3(256), dim3(512),
                                              params, 0, stream);
  if (err != hipSuccess) {
    // Fallback: proven 13-kernel path (identical math, alternating buffers 0/1)
    prep_kernel<<<512, 64, 0, stream>>>(hidden_state, group_track,
                                        W_emb, b_emb, W_ih, W_hh, b_ih, b_hh,
                                        W_pos, b_pos, W_rel, b_rel, W_pool, b_pool,
                                        lasts, hbfs, h_carry, WTf, Wp_bf,
                                        smallf, d_out);
    for (int t = 0; t < PRE; ++t) {
      int p = t & 1;
      pair_kernel<<<512, 256, 0, stream>>>(smallf, Wp_bf, WTf,
                                           lasts + p * 1024, lasts + (1 - p) * 1024,
                                           hbfs + p * 32768, hbfs + (1 - p) * 32768,
                                           h_carry, d_out, t);
    }
  }
}